// Round 4
// baseline (301.109 us; speedup 1.0000x reference)
//
#include <hip/hip_runtime.h>
#include <math.h>

#define F_IN 128
constexpr int SB = 256;

__global__ void zero_int(int* p, int n) {
    int i = blockIdx.x * 256 + threadIdx.x;
    if (i < n) p[i] = 0;
}

__global__ void count_deg(const int* __restrict__ dst, int* __restrict__ deg, int E, int N) {
    int e = blockIdx.x * 256 + threadIdx.x;
    if (e < E) atomicAdd(&deg[dst[e]], 1);
    else if (e < E + N) atomicAdd(&deg[e - E], 1);
}

// 3-kernel exclusive scan over n elements (n <= SB*SB)
__global__ void scan1(const int* __restrict__ in, int* __restrict__ out,
                      int* __restrict__ bsums, int n) {
    __shared__ int sm[SB];
    int i = blockIdx.x * SB + threadIdx.x;
    int v = (i < n) ? in[i] : 0;
    sm[threadIdx.x] = v;
    __syncthreads();
    for (int d = 1; d < SB; d <<= 1) {
        int t = (threadIdx.x >= d) ? sm[threadIdx.x - d] : 0;
        __syncthreads();
        sm[threadIdx.x] += t;
        __syncthreads();
    }
    if (i < n) out[i] = sm[threadIdx.x] - v;
    if (threadIdx.x == SB - 1) bsums[blockIdx.x] = sm[SB - 1];
}

__global__ void scan2(int* __restrict__ bsums, int nb) {
    __shared__ int sm[SB];
    int v = (threadIdx.x < nb) ? bsums[threadIdx.x] : 0;
    sm[threadIdx.x] = v;
    __syncthreads();
    for (int d = 1; d < SB; d <<= 1) {
        int t = (threadIdx.x >= d) ? sm[threadIdx.x - d] : 0;
        __syncthreads();
        sm[threadIdx.x] += t;
        __syncthreads();
    }
    if (threadIdx.x < nb) bsums[threadIdx.x] = sm[threadIdx.x] - v;
}

__global__ void scan3(int* __restrict__ off, int* __restrict__ cursor,
                      const int* __restrict__ bsums, int n, int ncur) {
    int i = blockIdx.x * SB + threadIdx.x;
    if (i < n) {
        int v = off[i] + bsums[blockIdx.x];
        off[i] = v;
        if (i < ncur) cursor[i] = v;
    }
}

__global__ void scatter_csr(const int* __restrict__ src, const int* __restrict__ dst,
                            int* __restrict__ cursor, int* __restrict__ csr_src,
                            int* __restrict__ csr_dst, int E, int N) {
    int e = blockIdx.x * 256 + threadIdx.x;
    if (e < E) {
        int d = dst[e];
        int p = atomicAdd(&cursor[d], 1);
        csr_src[p] = src[e];
        csr_dst[p] = d;
    } else if (e < E + N) {
        int i = e - E;
        int p = atomicAdd(&cursor[i], 1);
        csr_src[p] = i;
        csr_dst[p] = i;
    }
}

// Per-csr-slot softmax numerators: ex_t[hd][slot] = exp(leaky(als[src][hd]+ald[dst][hd]))
template <int HEADS>
__global__ void edge_ex(const float* __restrict__ als, const float* __restrict__ ald,
                        const int* __restrict__ cs, const int* __restrict__ cd,
                        float* __restrict__ ex_t, int ET) {
    int e = blockIdx.x * 256 + threadIdx.x;
    if (e >= ET) return;
    int s = cs[e], d = cd[e];
    float av[HEADS], bv[HEADS];
    if constexpr (HEADS == 4) {
        float4 a = ((const float4*)als)[s];
        float4 b = ((const float4*)ald)[d];
        av[0] = a.x; av[1] = a.y; av[2] = a.z; av[3] = a.w;
        bv[0] = b.x; bv[1] = b.y; bv[2] = b.z; bv[3] = b.w;
    } else if constexpr (HEADS == 2) {
        float2 a = ((const float2*)als)[s];
        float2 b = ((const float2*)ald)[d];
        av[0] = a.x; av[1] = a.y;
        bv[0] = b.x; bv[1] = b.y;
    } else {
        av[0] = als[s];
        bv[0] = ald[d];
    }
#pragma unroll
    for (int hd = 0; hd < HEADS; ++hd) {
        float lg = av[hd] + bv[hd];
        lg = lg > 0.f ? lg : 0.2f * lg;
        ex_t[(size_t)hd * ET + e] = __expf(lg);
    }
}

// LDS-tiled GEMM, C[M,BN] = A[M,128] * B[128,BN], fused per-(row,head)
// attention-logit epilogue.
template <int BN, int TN, int HEADS>
__global__ __launch_bounds__(512) void gemm_fused(
    const float* __restrict__ A, const float* __restrict__ B,
    const float* __restrict__ asrc, const float* __restrict__ adst,
    float* __restrict__ C, float* __restrict__ als, float* __restrict__ ald,
    int M) {
    constexpr int BM = 128, BK = 16, TM = 4, K = 128, OC = 32;
    constexpr int GROUP = OC / TN;
    __shared__ float As[BK][BM + 4];
    __shared__ float Bs[BK][BN];
    const int tx = threadIdx.x, ty = threadIdx.y;
    const int tid = ty * 16 + tx;
    const int row0 = blockIdx.x * BM;
    const int i0 = ty * TM;
    const int j0 = tx * TN;

    float acc[TM][TN];
#pragma unroll
    for (int m = 0; m < TM; ++m)
#pragma unroll
        for (int n = 0; n < TN; ++n) acc[m][n] = 0.f;

    const int ar = tid >> 2;
    const int ak = (tid & 3) * 4;
    int arow = row0 + ar;
    if (arow >= M) arow = M - 1;
    const float* Aptr = A + (size_t)arow * K + ak;
    const int bk = (BN == 128) ? (tid >> 5) : (tid >> 4);
    const int bc = (BN == 128) ? ((tid & 31) * 4) : ((tid & 15) * 4);
    const bool bact = (BN == 128) || (tid < 256);

    for (int kc = 0; kc < K; kc += BK) {
        float4 av = *(const float4*)(Aptr + kc);
        float4 bv;
        if (bact) bv = *(const float4*)(B + (size_t)(kc + bk) * BN + bc);
        __syncthreads();
        As[ak + 0][ar] = av.x;
        As[ak + 1][ar] = av.y;
        As[ak + 2][ar] = av.z;
        As[ak + 3][ar] = av.w;
        if (bact) *(float4*)&Bs[bk][bc] = bv;
        __syncthreads();
#pragma unroll
        for (int kk = 0; kk < BK; ++kk) {
            float4 a4 = *(const float4*)&As[kk][i0];
            float arr[TM] = {a4.x, a4.y, a4.z, a4.w};
            float br[TN];
            float4 b0 = *(const float4*)&Bs[kk][j0];
            br[0] = b0.x; br[1] = b0.y; br[2] = b0.z; br[3] = b0.w;
            if constexpr (TN == 8) {
                float4 b1 = *(const float4*)&Bs[kk][j0 + 4];
                br[4] = b1.x; br[5] = b1.y; br[6] = b1.z; br[7] = b1.w;
            }
#pragma unroll
            for (int m = 0; m < TM; ++m)
#pragma unroll
                for (int n = 0; n < TN; ++n) acc[m][n] += arr[m] * br[n];
        }
    }

    const int h0 = j0 / OC;
#pragma unroll
    for (int m = 0; m < TM; ++m) {
        int row = row0 + i0 + m;
        bool ok = row < M;
        if (ok) {
            float4 c0;
            c0.x = acc[m][0]; c0.y = acc[m][1]; c0.z = acc[m][2]; c0.w = acc[m][3];
            *(float4*)&C[(size_t)row * BN + j0] = c0;
            if constexpr (TN == 8) {
                float4 c1;
                c1.x = acc[m][4]; c1.y = acc[m][5]; c1.z = acc[m][6]; c1.w = acc[m][7];
                *(float4*)&C[(size_t)row * BN + j0 + 4] = c1;
            }
        }
        float ps = 0.f, pd = 0.f;
#pragma unroll
        for (int n = 0; n < TN; ++n) {
            ps += acc[m][n] * asrc[j0 + n];
            pd += acc[m][n] * adst[j0 + n];
        }
#pragma unroll
        for (int msk = 1; msk < GROUP; msk <<= 1) {
            ps += __shfl_xor(ps, msk, 64);
            pd += __shfl_xor(pd, msk, 64);
        }
        if (ok && (tx & (GROUP - 1)) == 0) {
            als[row * HEADS + h0] = ps;
            ald[row * HEADS + h0] = pd;
        }
    }
}

// Layer-1 aggregation: one wave per dst node, 2 ch/lane (float2). Precomputed
// per-edge ex; 2-wide, 2-deep software-pipelined gathers (4 loads in flight).
__global__ void gat_agg_l1(const float* __restrict__ h, const float* __restrict__ ex_t,
                           const float* __restrict__ bias,
                           const int* __restrict__ off, const int* __restrict__ csr_src,
                           float* __restrict__ out, int n, int ET) {
    int wid = (blockIdx.x * blockDim.x + threadIdx.x) >> 6;
    int lane = threadIdx.x & 63;
    if (wid >= n) return;
    const int hd = lane >> 4;
    const float2* h2 = (const float2*)h + lane;
    const float* exp_ = ex_t + (size_t)hd * ET;
    int e0 = off[wid], e1 = off[wid + 1];
    float Sx = 0.f, Sy = 0.f, D = 0.f;

    // prologue: slots A=e0 (always valid), B=e0+1 (maybe OOB)
    int iB = (e0 + 1 < e1) ? e0 + 1 : e0;
    int sA = csr_src[e0];
    int sB = csr_src[iB];
    float exA = exp_[e0];
    float exB = (e0 + 1 < e1) ? exp_[iB] : 0.f;
    float2 hA = h2[(size_t)sA * 64];
    float2 hB = h2[(size_t)sB * 64];

    int e = e0;
    for (; e + 2 < e1; e += 2) {
        int eD = e + 3;
        int iD = (eD < e1) ? eD : e1 - 1;
        int sC = csr_src[e + 2];
        int sD = csr_src[iD];
        float exC = exp_[e + 2];
        float exD = exp_[iD];
        exD = (eD < e1) ? exD : 0.f;
        float2 hC = h2[(size_t)sC * 64];
        float2 hD = h2[(size_t)sD * 64];
        D += exA + exB;
        Sx = fmaf(exA, hA.x, fmaf(exB, hB.x, Sx));
        Sy = fmaf(exA, hA.y, fmaf(exB, hB.y, Sy));
        exA = exC; hA = hC;
        exB = exD; hB = hD;
    }
    D += exA + exB;
    Sx = fmaf(exA, hA.x, fmaf(exB, hB.x, Sx));
    Sy = fmaf(exA, hA.y, fmaf(exB, hB.y, Sy));

    float inv = 1.f / D;
    float2 bv = ((const float2*)bias)[lane];
    float vx = Sx * inv + bv.x, vy = Sy * inv + bv.y;
    vx = vx > 0.f ? vx : (__expf(vx) - 1.f);
    vy = vy > 0.f ? vy : (__expf(vy) - 1.f);
    float2 o; o.x = vx; o.y = vy;
    ((float2*)out)[(size_t)wid * 64 + lane] = o;
}

// Layer-2 aggregation (C=64): same pipelined structure, 1 ch/lane, fused
// layer-3 feature head (h3 = elu(agg+b2) . W3, plus its logit terms).
__global__ void gat_agg_l2(const float* __restrict__ h, const float* __restrict__ ex_t,
                           const float* __restrict__ bias,
                           const int* __restrict__ off, const int* __restrict__ csr_src,
                           const float* __restrict__ W3, const float* __restrict__ as3,
                           const float* __restrict__ ad3, float* __restrict__ h3,
                           float* __restrict__ als3, float* __restrict__ ald3,
                           int n, int ET) {
    int wid = (blockIdx.x * blockDim.x + threadIdx.x) >> 6;
    int lane = threadIdx.x & 63;
    if (wid >= n) return;
    const int hd = lane >> 5;
    const float* hp = h + lane;
    const float* exp_ = ex_t + (size_t)hd * ET;
    int e0 = off[wid], e1 = off[wid + 1];
    float S = 0.f, D = 0.f;

    int iB = (e0 + 1 < e1) ? e0 + 1 : e0;
    int sA = csr_src[e0];
    int sB = csr_src[iB];
    float exA = exp_[e0];
    float exB = (e0 + 1 < e1) ? exp_[iB] : 0.f;
    float hA = hp[(size_t)sA * 64];
    float hB = hp[(size_t)sB * 64];

    int e = e0;
    for (; e + 2 < e1; e += 2) {
        int eD = e + 3;
        int iD = (eD < e1) ? eD : e1 - 1;
        int sC = csr_src[e + 2];
        int sD = csr_src[iD];
        float exC = exp_[e + 2];
        float exD = exp_[iD];
        exD = (eD < e1) ? exD : 0.f;
        float hC = hp[(size_t)sC * 64];
        float hD = hp[(size_t)sD * 64];
        D += exA + exB;
        S = fmaf(exA, hA, fmaf(exB, hB, S));
        exA = exC; hA = hC;
        exB = exD; hB = hD;
    }
    D += exA + exB;
    S = fmaf(exA, hA, fmaf(exB, hB, S));

    float v = S / D + bias[lane];
    v = v > 0.f ? v : (__expf(v) - 1.f);     // a2[wid][lane]
    float r = v * W3[lane];
#pragma unroll
    for (int msk = 1; msk < 64; msk <<= 1) r += __shfl_xor(r, msk, 64);
    if (lane == 0) {
        h3[wid] = r;
        als3[wid] = r * as3[0];
        ald3[wid] = r * ad3[0];
    }
}

// Layer-3 aggregation: scalar channel, thread per node, 1-deep prefetch.
__global__ void gat_agg1(const float* __restrict__ h, const float* __restrict__ ex_t,
                         const float* __restrict__ bias,
                         const int* __restrict__ off, const int* __restrict__ csr_src,
                         float* __restrict__ out, int n) {
    int i = blockIdx.x * blockDim.x + threadIdx.x;
    if (i >= n) return;
    int e0 = off[i], e1 = off[i + 1];
    float S = 0.f, D = 0.f;
    int s = csr_src[e0];
    float ex = ex_t[e0];
    float hv = h[s];
    for (int e = e0; e < e1; ++e) {
        int ib = (e + 1 < e1) ? e + 1 : e;
        int sn = csr_src[ib];
        float exn = ex_t[ib];
        exn = (e + 1 < e1) ? exn : 0.f;
        float hn = h[sn];
        D += ex;
        S = fmaf(ex, hv, S);
        ex = exn; hv = hn;
    }
    out[i] = S / D + bias[0];
}

extern "C" void kernel_launch(void* const* d_in, const int* in_sizes, int n_in,
                              void* d_out, int out_size, void* d_ws, size_t ws_size,
                              hipStream_t stream) {
    const float* x   = (const float*)d_in[0];
    const int*   ei  = (const int*)d_in[1];
    const float* W1  = (const float*)d_in[2];
    const float* as1 = (const float*)d_in[3];
    const float* ad1 = (const float*)d_in[4];
    const float* b1  = (const float*)d_in[5];
    const float* W2  = (const float*)d_in[6];
    const float* as2 = (const float*)d_in[7];
    const float* ad2 = (const float*)d_in[8];
    const float* b2  = (const float*)d_in[9];
    const float* W3  = (const float*)d_in[10];
    const float* as3 = (const float*)d_in[11];
    const float* ad3 = (const float*)d_in[12];
    const float* b3  = (const float*)d_in[13];
    float* out = (float*)d_out;

    const int N = in_sizes[0] / F_IN;  // 50000
    const int E = in_sizes[1] / 2;     // 800000
    const int ET = E + N;

    char* w = (char*)d_ws;
    size_t o = 0;
    auto alloc = [&](size_t bytes) -> void* {
        void* p = w + o;
        o += (bytes + 255) & ~(size_t)255;
        return p;
    };
    float* h1   = (float*)alloc((size_t)N * 128 * 4);  // reused: h2, h3 after agg_l1
    float* a1   = (float*)alloc((size_t)N * 128 * 4);
    float* als  = (float*)alloc((size_t)N * 4 * 4);
    float* ald  = (float*)alloc((size_t)N * 4 * 4);
    float* als3 = (float*)alloc((size_t)N * 4);
    float* ald3 = (float*)alloc((size_t)N * 4);
    int* deg    = (int*)alloc((size_t)(N + 1) * 4);
    int* off    = (int*)alloc((size_t)(N + 1) * 4);
    int* cursor = (int*)alloc((size_t)N * 4);
    int* bsums  = (int*)alloc(1024);
    int* csr    = (int*)alloc((size_t)ET * 4);
    int* csrd   = (int*)alloc((size_t)ET * 4);
    float* exb  = (float*)alloc((size_t)4 * ET * 4);   // reused per layer

    float* h2 = h1;                 // h1 dead after agg_l1
    float* h3 = h1 + (size_t)N * 64;

    const int* esrc = ei;
    const int* edst = ei + E;

    // ---- CSR build (dst-sorted incoming-edge lists, with dst per slot) ----
    zero_int<<<(N + 1 + 255) / 256, 256, 0, stream>>>(deg, N + 1);
    count_deg<<<(ET + 255) / 256, 256, 0, stream>>>(edst, deg, E, N);
    int n1 = N + 1;
    int nb = (n1 + SB - 1) / SB;
    scan1<<<nb, SB, 0, stream>>>(deg, off, bsums, n1);
    scan2<<<1, SB, 0, stream>>>(bsums, nb);
    scan3<<<nb, SB, 0, stream>>>(off, cursor, bsums, n1, N);
    scatter_csr<<<(ET + 255) / 256, 256, 0, stream>>>(esrc, edst, cursor, csr, csrd, E, N);

    const int gblk = (N + 127) / 128;
    const int eblk = (ET + 255) / 256;

    // ---- Layer 1: 128 -> 4 heads x 32, concat, ELU ----
    gemm_fused<128, 8, 4><<<gblk, dim3(16, 32), 0, stream>>>(
        x, W1, as1, ad1, h1, als, ald, N);
    edge_ex<4><<<eblk, 256, 0, stream>>>(als, ald, csr, csrd, exb, ET);
    gat_agg_l1<<<(N * 64 + 255) / 256, 256, 0, stream>>>(
        h1, exb, b1, off, csr, a1, N, ET);

    // ---- Layer 2: 128 -> 2 heads x 32, concat, ELU (+ fused layer-3 head) ----
    gemm_fused<64, 4, 2><<<gblk, dim3(16, 32), 0, stream>>>(
        a1, W2, as2, ad2, h2, als, ald, N);
    edge_ex<2><<<eblk, 256, 0, stream>>>(als, ald, csr, csrd, exb, ET);
    gat_agg_l2<<<(N * 64 + 255) / 256, 256, 0, stream>>>(
        h2, exb, b2, off, csr, W3, as3, ad3, h3, als3, ald3, N, ET);

    // ---- Layer 3: aggregation of scalar feature ----
    edge_ex<1><<<eblk, 256, 0, stream>>>(als3, ald3, csr, csrd, exb, ET);
    gat_agg1<<<(N + 255) / 256, 256, 0, stream>>>(h3, exb, b3, off, csr, out, N);
}

// Round 6
// 288.244 us; speedup vs baseline: 1.0446x; 1.0446x over previous
//
#include <hip/hip_runtime.h>
#include <math.h>

#define F_IN 128
constexpr int SB = 256;

__global__ void zero_int(int* p, int n) {
    int i = blockIdx.x * 256 + threadIdx.x;
    if (i < n) p[i] = 0;
}

__global__ void count_deg(const int* __restrict__ dst, int* __restrict__ deg, int E, int N) {
    int e = blockIdx.x * 256 + threadIdx.x;
    if (e < E) atomicAdd(&deg[dst[e]], 1);
    else if (e < E + N) atomicAdd(&deg[e - E], 1);
}

// 3-kernel exclusive scan over n elements (n <= SB*SB)
__global__ void scan1(const int* __restrict__ in, int* __restrict__ out,
                      int* __restrict__ bsums, int n) {
    __shared__ int sm[SB];
    int i = blockIdx.x * SB + threadIdx.x;
    int v = (i < n) ? in[i] : 0;
    sm[threadIdx.x] = v;
    __syncthreads();
    for (int d = 1; d < SB; d <<= 1) {
        int t = (threadIdx.x >= d) ? sm[threadIdx.x - d] : 0;
        __syncthreads();
        sm[threadIdx.x] += t;
        __syncthreads();
    }
    if (i < n) out[i] = sm[threadIdx.x] - v;
    if (threadIdx.x == SB - 1) bsums[blockIdx.x] = sm[SB - 1];
}

__global__ void scan2(int* __restrict__ bsums, int nb) {
    __shared__ int sm[SB];
    int v = (threadIdx.x < nb) ? bsums[threadIdx.x] : 0;
    sm[threadIdx.x] = v;
    __syncthreads();
    for (int d = 1; d < SB; d <<= 1) {
        int t = (threadIdx.x >= d) ? sm[threadIdx.x - d] : 0;
        __syncthreads();
        sm[threadIdx.x] += t;
        __syncthreads();
    }
    if (threadIdx.x < nb) bsums[threadIdx.x] = sm[threadIdx.x] - v;
}

__global__ void scan3(int* __restrict__ off, int* __restrict__ cursor,
                      const int* __restrict__ bsums, int n, int ncur) {
    int i = blockIdx.x * SB + threadIdx.x;
    if (i < n) {
        int v = off[i] + bsums[blockIdx.x];
        off[i] = v;
        if (i < ncur) cursor[i] = v;
    }
}

// Single 8B store per edge: one cache line touched instead of two.
__global__ void scatter_csr(const int* __restrict__ src, const int* __restrict__ dst,
                            int* __restrict__ cursor, int2* __restrict__ csr_sd,
                            int E, int N) {
    int e = blockIdx.x * 256 + threadIdx.x;
    if (e < E) {
        int s = src[e], d = dst[e];
        int p = atomicAdd(&cursor[d], 1);
        csr_sd[p] = make_int2(s, d);
    } else if (e < E + N) {
        int i = e - E;
        int p = atomicAdd(&cursor[i], 1);
        csr_sd[p] = make_int2(i, i);
    }
}

// Per-csr-slot softmax numerators: ex_t[hd][slot] = exp(leaky(als[src][hd]+ald[dst][hd]))
template <int HEADS>
__global__ void edge_ex(const float* __restrict__ als, const float* __restrict__ ald,
                        const int2* __restrict__ csr_sd, float* __restrict__ ex_t, int ET) {
    int e = blockIdx.x * 256 + threadIdx.x;
    if (e >= ET) return;
    int2 sd = csr_sd[e];
    int s = sd.x, d = sd.y;
    float av[HEADS], bv[HEADS];
    if constexpr (HEADS == 4) {
        float4 a = ((const float4*)als)[s];
        float4 b = ((const float4*)ald)[d];
        av[0] = a.x; av[1] = a.y; av[2] = a.z; av[3] = a.w;
        bv[0] = b.x; bv[1] = b.y; bv[2] = b.z; bv[3] = b.w;
    } else if constexpr (HEADS == 2) {
        float2 a = ((const float2*)als)[s];
        float2 b = ((const float2*)ald)[d];
        av[0] = a.x; av[1] = a.y;
        bv[0] = b.x; bv[1] = b.y;
    } else {
        av[0] = als[s];
        bv[0] = ald[d];
    }
#pragma unroll
    for (int hd = 0; hd < HEADS; ++hd) {
        float lg = av[hd] + bv[hd];
        lg = lg > 0.f ? lg : 0.2f * lg;
        ex_t[(size_t)hd * ET + e] = __expf(lg);
    }
}

// LDS-tiled GEMM, C[M,BN] = A[M,128] * B[128,BN], fused per-(row,head)
// attention-logit epilogue.
template <int BN, int TN, int HEADS>
__global__ __launch_bounds__(512) void gemm_fused(
    const float* __restrict__ A, const float* __restrict__ B,
    const float* __restrict__ asrc, const float* __restrict__ adst,
    float* __restrict__ C, float* __restrict__ als, float* __restrict__ ald,
    int M) {
    constexpr int BM = 128, BK = 16, TM = 4, K = 128, OC = 32;
    constexpr int GROUP = OC / TN;
    __shared__ float As[BK][BM + 4];
    __shared__ float Bs[BK][BN];
    const int tx = threadIdx.x, ty = threadIdx.y;
    const int tid = ty * 16 + tx;
    const int row0 = blockIdx.x * BM;
    const int i0 = ty * TM;
    const int j0 = tx * TN;

    float acc[TM][TN];
#pragma unroll
    for (int m = 0; m < TM; ++m)
#pragma unroll
        for (int n = 0; n < TN; ++n) acc[m][n] = 0.f;

    const int ar = tid >> 2;
    const int ak = (tid & 3) * 4;
    int arow = row0 + ar;
    if (arow >= M) arow = M - 1;
    const float* Aptr = A + (size_t)arow * K + ak;
    const int bk = (BN == 128) ? (tid >> 5) : (tid >> 4);
    const int bc = (BN == 128) ? ((tid & 31) * 4) : ((tid & 15) * 4);
    const bool bact = (BN == 128) || (tid < 256);

    for (int kc = 0; kc < K; kc += BK) {
        float4 av = *(const float4*)(Aptr + kc);
        float4 bv;
        if (bact) bv = *(const float4*)(B + (size_t)(kc + bk) * BN + bc);
        __syncthreads();
        As[ak + 0][ar] = av.x;
        As[ak + 1][ar] = av.y;
        As[ak + 2][ar] = av.z;
        As[ak + 3][ar] = av.w;
        if (bact) *(float4*)&Bs[bk][bc] = bv;
        __syncthreads();
#pragma unroll
        for (int kk = 0; kk < BK; ++kk) {
            float4 a4 = *(const float4*)&As[kk][i0];
            float arr[TM] = {a4.x, a4.y, a4.z, a4.w};
            float br[TN];
            float4 b0 = *(const float4*)&Bs[kk][j0];
            br[0] = b0.x; br[1] = b0.y; br[2] = b0.z; br[3] = b0.w;
            if constexpr (TN == 8) {
                float4 b1 = *(const float4*)&Bs[kk][j0 + 4];
                br[4] = b1.x; br[5] = b1.y; br[6] = b1.z; br[7] = b1.w;
            }
#pragma unroll
            for (int m = 0; m < TM; ++m)
#pragma unroll
                for (int n = 0; n < TN; ++n) acc[m][n] += arr[m] * br[n];
        }
    }

    const int h0 = j0 / OC;
#pragma unroll
    for (int m = 0; m < TM; ++m) {
        int row = row0 + i0 + m;
        bool ok = row < M;
        if (ok) {
            float4 c0;
            c0.x = acc[m][0]; c0.y = acc[m][1]; c0.z = acc[m][2]; c0.w = acc[m][3];
            *(float4*)&C[(size_t)row * BN + j0] = c0;
            if constexpr (TN == 8) {
                float4 c1;
                c1.x = acc[m][4]; c1.y = acc[m][5]; c1.z = acc[m][6]; c1.w = acc[m][7];
                *(float4*)&C[(size_t)row * BN + j0 + 4] = c1;
            }
        }
        float ps = 0.f, pd = 0.f;
#pragma unroll
        for (int n = 0; n < TN; ++n) {
            ps += acc[m][n] * asrc[j0 + n];
            pd += acc[m][n] * adst[j0 + n];
        }
#pragma unroll
        for (int msk = 1; msk < GROUP; msk <<= 1) {
            ps += __shfl_xor(ps, msk, 64);
            pd += __shfl_xor(pd, msk, 64);
        }
        if (ok && (tx & (GROUP - 1)) == 0) {
            als[row * HEADS + h0] = ps;
            ald[row * HEADS + h0] = pd;
        }
    }
}

// Layer-1 aggregation: one wave per dst node, 2 ch/lane (float2). Precomputed
// per-edge ex; 4-wide software pipeline (12 loads in flight per wave).
__global__ void gat_agg_l1(const float* __restrict__ h, const float* __restrict__ ex_t,
                           const float* __restrict__ bias,
                           const int* __restrict__ off, const int2* __restrict__ csr_sd,
                           float* __restrict__ out, int n, int ET) {
    int wid = (blockIdx.x * blockDim.x + threadIdx.x) >> 6;
    int lane = threadIdx.x & 63;
    if (wid >= n) return;
    const int hd = lane >> 4;
    const float2* h2 = (const float2*)h + lane;
    const float* exp_ = ex_t + (size_t)hd * ET;
    int e0 = off[wid], e1 = off[wid + 1];
    float Sx = 0.f, Sy = 0.f, D = 0.f;

    float ex[4];
    float2 hv[4];
#pragma unroll
    for (int p = 0; p < 4; ++p) {
        int ee = e0 + p;
        int ie = (ee < e1) ? ee : e1 - 1;
        int s = csr_sd[ie].x;
        float exv = exp_[ie];
        ex[p] = (ee < e1) ? exv : 0.f;
        hv[p] = h2[(size_t)s * 64];
    }
    int e = e0;
    for (; e + 4 < e1; e += 4) {
        float nex[4];
        float2 nhv[4];
#pragma unroll
        for (int p = 0; p < 4; ++p) {
            int ee = e + 4 + p;
            int ie = (ee < e1) ? ee : e1 - 1;
            int s = csr_sd[ie].x;
            float exv = exp_[ie];
            nex[p] = (ee < e1) ? exv : 0.f;
            nhv[p] = h2[(size_t)s * 64];
        }
#pragma unroll
        for (int p = 0; p < 4; ++p) {
            D += ex[p];
            Sx = fmaf(ex[p], hv[p].x, Sx);
            Sy = fmaf(ex[p], hv[p].y, Sy);
            ex[p] = nex[p];
            hv[p] = nhv[p];
        }
    }
#pragma unroll
    for (int p = 0; p < 4; ++p) {
        D += ex[p];
        Sx = fmaf(ex[p], hv[p].x, Sx);
        Sy = fmaf(ex[p], hv[p].y, Sy);
    }

    float inv = 1.f / D;
    float2 bv = ((const float2*)bias)[lane];
    float vx = Sx * inv + bv.x, vy = Sy * inv + bv.y;
    vx = vx > 0.f ? vx : (__expf(vx) - 1.f);
    vy = vy > 0.f ? vy : (__expf(vy) - 1.f);
    float2 o; o.x = vx; o.y = vy;
    ((float2*)out)[(size_t)wid * 64 + lane] = o;
}

// Layer-2 aggregation (C=64): 4-wide pipeline, 1 ch/lane, fused layer-3
// feature head (h3 = elu(agg+b2) . W3, plus its logit terms).
__global__ void gat_agg_l2(const float* __restrict__ h, const float* __restrict__ ex_t,
                           const float* __restrict__ bias,
                           const int* __restrict__ off, const int2* __restrict__ csr_sd,
                           const float* __restrict__ W3, const float* __restrict__ as3,
                           const float* __restrict__ ad3, float* __restrict__ h3,
                           float* __restrict__ als3, float* __restrict__ ald3,
                           int n, int ET) {
    int wid = (blockIdx.x * blockDim.x + threadIdx.x) >> 6;
    int lane = threadIdx.x & 63;
    if (wid >= n) return;
    const int hd = lane >> 5;
    const float* hp = h + lane;
    const float* exp_ = ex_t + (size_t)hd * ET;
    int e0 = off[wid], e1 = off[wid + 1];
    float S = 0.f, D = 0.f;

    float ex[4], hv[4];
#pragma unroll
    for (int p = 0; p < 4; ++p) {
        int ee = e0 + p;
        int ie = (ee < e1) ? ee : e1 - 1;
        int s = csr_sd[ie].x;
        float exv = exp_[ie];
        ex[p] = (ee < e1) ? exv : 0.f;
        hv[p] = hp[(size_t)s * 64];
    }
    int e = e0;
    for (; e + 4 < e1; e += 4) {
        float nex[4], nhv[4];
#pragma unroll
        for (int p = 0; p < 4; ++p) {
            int ee = e + 4 + p;
            int ie = (ee < e1) ? ee : e1 - 1;
            int s = csr_sd[ie].x;
            float exv = exp_[ie];
            nex[p] = (ee < e1) ? exv : 0.f;
            nhv[p] = hp[(size_t)s * 64];
        }
#pragma unroll
        for (int p = 0; p < 4; ++p) {
            D += ex[p];
            S = fmaf(ex[p], hv[p], S);
            ex[p] = nex[p];
            hv[p] = nhv[p];
        }
    }
#pragma unroll
    for (int p = 0; p < 4; ++p) {
        D += ex[p];
        S = fmaf(ex[p], hv[p], S);
    }

    float v = S / D + bias[lane];
    v = v > 0.f ? v : (__expf(v) - 1.f);     // a2[wid][lane]
    float r = v * W3[lane];
#pragma unroll
    for (int msk = 1; msk < 64; msk <<= 1) r += __shfl_xor(r, msk, 64);
    if (lane == 0) {
        h3[wid] = r;
        als3[wid] = r * as3[0];
        ald3[wid] = r * ad3[0];
    }
}

// Layer-3 aggregation: scalar channel, thread per node, 2-wide pipeline.
__global__ void gat_agg1(const float* __restrict__ h, const float* __restrict__ ex_t,
                         const float* __restrict__ bias,
                         const int* __restrict__ off, const int2* __restrict__ csr_sd,
                         float* __restrict__ out, int n) {
    int i = blockIdx.x * blockDim.x + threadIdx.x;
    if (i >= n) return;
    int e0 = off[i], e1 = off[i + 1];
    float S = 0.f, D = 0.f;
    float ex[2], hv[2];
#pragma unroll
    for (int p = 0; p < 2; ++p) {
        int ee = e0 + p;
        int ie = (ee < e1) ? ee : e1 - 1;
        int s = csr_sd[ie].x;
        float exv = ex_t[ie];
        ex[p] = (ee < e1) ? exv : 0.f;
        hv[p] = h[s];
    }
    int e = e0;
    for (; e + 2 < e1; e += 2) {
#pragma unroll
        for (int p = 0; p < 2; ++p) {
            int ee = e + 2 + p;
            int ie = (ee < e1) ? ee : e1 - 1;
            int s = csr_sd[ie].x;
            float exv = ex_t[ie];
            float nex = (ee < e1) ? exv : 0.f;
            float nhv = h[s];
            D += ex[p];
            S = fmaf(ex[p], hv[p], S);
            ex[p] = nex;
            hv[p] = nhv;
        }
    }
#pragma unroll
    for (int p = 0; p < 2; ++p) {
        D += ex[p];
        S = fmaf(ex[p], hv[p], S);
    }
    out[i] = S / D + bias[0];
}

extern "C" void kernel_launch(void* const* d_in, const int* in_sizes, int n_in,
                              void* d_out, int out_size, void* d_ws, size_t ws_size,
                              hipStream_t stream) {
    const float* x   = (const float*)d_in[0];
    const int*   ei  = (const int*)d_in[1];
    const float* W1  = (const float*)d_in[2];
    const float* as1 = (const float*)d_in[3];
    const float* ad1 = (const float*)d_in[4];
    const float* b1  = (const float*)d_in[5];
    const float* W2  = (const float*)d_in[6];
    const float* as2 = (const float*)d_in[7];
    const float* ad2 = (const float*)d_in[8];
    const float* b2  = (const float*)d_in[9];
    const float* W3  = (const float*)d_in[10];
    const float* as3 = (const float*)d_in[11];
    const float* ad3 = (const float*)d_in[12];
    const float* b3  = (const float*)d_in[13];
    float* out = (float*)d_out;

    const int N = in_sizes[0] / F_IN;  // 50000
    const int E = in_sizes[1] / 2;     // 800000
    const int ET = E + N;

    char* w = (char*)d_ws;
    size_t o = 0;
    auto alloc = [&](size_t bytes) -> void* {
        void* p = w + o;
        o += (bytes + 255) & ~(size_t)255;
        return p;
    };
    float* h1   = (float*)alloc((size_t)N * 128 * 4);  // reused: h2, h3 after agg_l1
    float* a1   = (float*)alloc((size_t)N * 128 * 4);
    float* als  = (float*)alloc((size_t)N * 4 * 4);
    float* ald  = (float*)alloc((size_t)N * 4 * 4);
    float* als3 = (float*)alloc((size_t)N * 4);
    float* ald3 = (float*)alloc((size_t)N * 4);
    int* deg    = (int*)alloc((size_t)(N + 1) * 4);
    int* off    = (int*)alloc((size_t)(N + 1) * 4);
    int* cursor = (int*)alloc((size_t)N * 4);
    int* bsums  = (int*)alloc(1024);
    int2* csr_sd = (int2*)alloc((size_t)ET * 8);
    float* exb  = (float*)alloc((size_t)4 * ET * 4);   // reused per layer

    float* h2 = h1;                 // h1 dead after agg_l1
    float* h3 = h1 + (size_t)N * 64;

    const int* esrc = ei;
    const int* edst = ei + E;

    // ---- CSR build (dst-sorted incoming-edge lists, int2{src,dst} per slot) ----
    zero_int<<<(N + 1 + 255) / 256, 256, 0, stream>>>(deg, N + 1);
    count_deg<<<(ET + 255) / 256, 256, 0, stream>>>(edst, deg, E, N);
    int n1 = N + 1;
    int nb = (n1 + SB - 1) / SB;
    scan1<<<nb, SB, 0, stream>>>(deg, off, bsums, n1);
    scan2<<<1, SB, 0, stream>>>(bsums, nb);
    scan3<<<nb, SB, 0, stream>>>(off, cursor, bsums, n1, N);
    scatter_csr<<<(ET + 255) / 256, 256, 0, stream>>>(esrc, edst, cursor, csr_sd, E, N);

    const int gblk = (N + 127) / 128;
    const int eblk = (ET + 255) / 256;

    // ---- Layer 1: 128 -> 4 heads x 32, concat, ELU ----
    gemm_fused<128, 8, 4><<<gblk, dim3(16, 32), 0, stream>>>(
        x, W1, as1, ad1, h1, als, ald, N);
    edge_ex<4><<<eblk, 256, 0, stream>>>(als, ald, csr_sd, exb, ET);
    gat_agg_l1<<<(N * 64 + 255) / 256, 256, 0, stream>>>(
        h1, exb, b1, off, csr_sd, a1, N, ET);

    // ---- Layer 2: 128 -> 2 heads x 32, concat, ELU (+ fused layer-3 head) ----
    gemm_fused<64, 4, 2><<<gblk, dim3(16, 32), 0, stream>>>(
        a1, W2, as2, ad2, h2, als, ald, N);
    edge_ex<2><<<eblk, 256, 0, stream>>>(als, ald, csr_sd, exb, ET);
    gat_agg_l2<<<(N * 64 + 255) / 256, 256, 0, stream>>>(
        h2, exb, b2, off, csr_sd, W3, as3, ad3, h3, als3, ald3, N, ET);

    // ---- Layer 3: aggregation of scalar feature ----
    edge_ex<1><<<eblk, 256, 0, stream>>>(als3, ald3, csr_sd, exb, ET);
    gat_agg1<<<(N + 255) / 256, 256, 0, stream>>>(h3, exb, b3, off, csr_sd, out, N);
}

// Round 8
// 253.177 us; speedup vs baseline: 1.1893x; 1.1385x over previous
//
#include <hip/hip_runtime.h>
#include <hip/hip_fp16.h>
#include <math.h>

#define F_IN 128
constexpr int SB = 256;

__global__ void zero_int(int* p, int n) {
    int i = blockIdx.x * 256 + threadIdx.x;
    if (i < n) p[i] = 0;
}

// 4 edges/thread, int4 loads, fire-and-forget atomics (self-loops folded into scan).
__global__ void count_deg4(const int* __restrict__ dst, int* __restrict__ deg, int E) {
    int t = blockIdx.x * 256 + threadIdx.x;
    int base = t * 4;
    if (base + 3 < E) {
        int4 d = *(const int4*)(dst + base);
        atomicAdd(&deg[d.x], 1);
        atomicAdd(&deg[d.y], 1);
        atomicAdd(&deg[d.z], 1);
        atomicAdd(&deg[d.w], 1);
    } else {
        for (int k = 0; k < 4; ++k) {
            int e = base + k;
            if (e < E) atomicAdd(&deg[dst[e]], 1);
        }
    }
}

// 3-kernel exclusive scan over n elements (n <= SB*SB); +1 per element for i<selfN
__global__ void scan1(const int* __restrict__ in, int* __restrict__ out,
                      int* __restrict__ bsums, int n, int selfN) {
    __shared__ int sm[SB];
    int i = blockIdx.x * SB + threadIdx.x;
    int v = (i < n) ? (in[i] + (i < selfN ? 1 : 0)) : 0;
    sm[threadIdx.x] = v;
    __syncthreads();
    for (int d = 1; d < SB; d <<= 1) {
        int t = (threadIdx.x >= d) ? sm[threadIdx.x - d] : 0;
        __syncthreads();
        sm[threadIdx.x] += t;
        __syncthreads();
    }
    if (i < n) out[i] = sm[threadIdx.x] - v;
    if (threadIdx.x == SB - 1) bsums[blockIdx.x] = sm[SB - 1];
}

__global__ void scan2(int* __restrict__ bsums, int nb) {
    __shared__ int sm[SB];
    int v = (threadIdx.x < nb) ? bsums[threadIdx.x] : 0;
    sm[threadIdx.x] = v;
    __syncthreads();
    for (int d = 1; d < SB; d <<= 1) {
        int t = (threadIdx.x >= d) ? sm[threadIdx.x - d] : 0;
        __syncthreads();
        sm[threadIdx.x] += t;
        __syncthreads();
    }
    if (threadIdx.x < nb) bsums[threadIdx.x] = sm[threadIdx.x] - v;
}

__global__ void scan3(int* __restrict__ off, int* __restrict__ cursor,
                      const int* __restrict__ bsums, int n, int ncur) {
    int i = blockIdx.x * SB + threadIdx.x;
    if (i < n) {
        int v = off[i] + bsums[blockIdx.x];
        off[i] = v;
        if (i < ncur) cursor[i] = v;
    }
}

// 4 edges/thread: 4 independent atomic->store chains in flight.
__global__ void scatter_csr4(const int* __restrict__ src, const int* __restrict__ dst,
                             int* __restrict__ cursor, int2* __restrict__ csr_sd,
                             int E, int N) {
    int t = blockIdx.x * 256 + threadIdx.x;
    int E4 = (E + 3) >> 2;
    if (t < E4) {
        int base = t * 4;
        if (base + 3 < E) {
            int4 s4 = *(const int4*)(src + base);
            int4 d4 = *(const int4*)(dst + base);
            int p0 = atomicAdd(&cursor[d4.x], 1);
            int p1 = atomicAdd(&cursor[d4.y], 1);
            int p2 = atomicAdd(&cursor[d4.z], 1);
            int p3 = atomicAdd(&cursor[d4.w], 1);
            csr_sd[p0] = make_int2(s4.x, d4.x);
            csr_sd[p1] = make_int2(s4.y, d4.y);
            csr_sd[p2] = make_int2(s4.z, d4.z);
            csr_sd[p3] = make_int2(s4.w, d4.w);
        } else {
            for (int k = 0; k < 4; ++k) {
                int e = base + k;
                if (e < E) {
                    int s = src[e], d = dst[e];
                    int p = atomicAdd(&cursor[d], 1);
                    csr_sd[p] = make_int2(s, d);
                }
            }
        }
    } else {
        int i = t - E4;
        if (i < N) {
            int p = atomicAdd(&cursor[i], 1);
            csr_sd[p] = make_int2(i, i);
        }
    }
}

// Per-csr-slot softmax numerators: ex_t[hd][slot] = exp(leaky(als[src][hd]+ald[dst][hd]))
template <int HEADS>
__global__ void edge_ex(const float* __restrict__ als, const float* __restrict__ ald,
                        const int2* __restrict__ csr_sd, float* __restrict__ ex_t, int ET) {
    int e = blockIdx.x * 256 + threadIdx.x;
    if (e >= ET) return;
    int2 sd = csr_sd[e];
    int s = sd.x, d = sd.y;
    float av[HEADS], bv[HEADS];
    if constexpr (HEADS == 4) {
        float4 a = ((const float4*)als)[s];
        float4 b = ((const float4*)ald)[d];
        av[0] = a.x; av[1] = a.y; av[2] = a.z; av[3] = a.w;
        bv[0] = b.x; bv[1] = b.y; bv[2] = b.z; bv[3] = b.w;
    } else if constexpr (HEADS == 2) {
        float2 a = ((const float2*)als)[s];
        float2 b = ((const float2*)ald)[d];
        av[0] = a.x; av[1] = a.y;
        bv[0] = b.x; bv[1] = b.y;
    } else {
        av[0] = als[s];
        bv[0] = ald[d];
    }
#pragma unroll
    for (int hd = 0; hd < HEADS; ++hd) {
        float lg = av[hd] + bv[hd];
        lg = lg > 0.f ? lg : 0.2f * lg;
        ex_t[(size_t)hd * ET + e] = __expf(lg);
    }
}

// LDS-tiled GEMM, C_half[M,BN] = A[M,128] * B[128,BN] (fp16 output for cheap
// downstream gathers), fused per-(row,head) fp32 attention-logit epilogue.
template <int BN, int TN, int HEADS>
__global__ __launch_bounds__(512) void gemm_fused(
    const float* __restrict__ A, const float* __restrict__ B,
    const float* __restrict__ asrc, const float* __restrict__ adst,
    __half* __restrict__ C, float* __restrict__ als, float* __restrict__ ald,
    int M) {
    constexpr int BM = 128, BK = 16, TM = 4, K = 128, OC = 32;
    constexpr int GROUP = OC / TN;
    __shared__ float As[BK][BM + 4];
    __shared__ float Bs[BK][BN];
    const int tx = threadIdx.x, ty = threadIdx.y;
    const int tid = ty * 16 + tx;
    const int row0 = blockIdx.x * BM;
    const int i0 = ty * TM;
    const int j0 = tx * TN;

    float acc[TM][TN];
#pragma unroll
    for (int m = 0; m < TM; ++m)
#pragma unroll
        for (int n = 0; n < TN; ++n) acc[m][n] = 0.f;

    const int ar = tid >> 2;
    const int ak = (tid & 3) * 4;
    int arow = row0 + ar;
    if (arow >= M) arow = M - 1;
    const float* Aptr = A + (size_t)arow * K + ak;
    const int bk = (BN == 128) ? (tid >> 5) : (tid >> 4);
    const int bc = (BN == 128) ? ((tid & 31) * 4) : ((tid & 15) * 4);
    const bool bact = (BN == 128) || (tid < 256);

    for (int kc = 0; kc < K; kc += BK) {
        float4 av = *(const float4*)(Aptr + kc);
        float4 bv;
        if (bact) bv = *(const float4*)(B + (size_t)(kc + bk) * BN + bc);
        __syncthreads();
        As[ak + 0][ar] = av.x;
        As[ak + 1][ar] = av.y;
        As[ak + 2][ar] = av.z;
        As[ak + 3][ar] = av.w;
        if (bact) *(float4*)&Bs[bk][bc] = bv;
        __syncthreads();
#pragma unroll
        for (int kk = 0; kk < BK; ++kk) {
            float4 a4 = *(const float4*)&As[kk][i0];
            float arr[TM] = {a4.x, a4.y, a4.z, a4.w};
            float br[TN];
            float4 b0 = *(const float4*)&Bs[kk][j0];
            br[0] = b0.x; br[1] = b0.y; br[2] = b0.z; br[3] = b0.w;
            if constexpr (TN == 8) {
                float4 b1 = *(const float4*)&Bs[kk][j0 + 4];
                br[4] = b1.x; br[5] = b1.y; br[6] = b1.z; br[7] = b1.w;
            }
#pragma unroll
            for (int m = 0; m < TM; ++m)
#pragma unroll
                for (int n = 0; n < TN; ++n) acc[m][n] += arr[m] * br[n];
        }
    }

    const int h0 = j0 / OC;
#pragma unroll
    for (int m = 0; m < TM; ++m) {
        int row = row0 + i0 + m;
        bool ok = row < M;
        if (ok) {
            alignas(16) __half2 ph[TN / 2];
#pragma unroll
            for (int n2 = 0; n2 < TN / 2; ++n2)
                ph[n2] = __floats2half2_rn(acc[m][2 * n2], acc[m][2 * n2 + 1]);
            if constexpr (TN == 8)
                *(uint4*)&C[(size_t)row * BN + j0] = *(uint4*)ph;
            else
                *(uint2*)&C[(size_t)row * BN + j0] = *(uint2*)ph;
        }
        float ps = 0.f, pd = 0.f;
#pragma unroll
        for (int n = 0; n < TN; ++n) {
            ps += acc[m][n] * asrc[j0 + n];
            pd += acc[m][n] * adst[j0 + n];
        }
#pragma unroll
        for (int msk = 1; msk < GROUP; msk <<= 1) {
            ps += __shfl_xor(ps, msk, 64);
            pd += __shfl_xor(pd, msk, 64);
        }
        if (ok && (tx & (GROUP - 1)) == 0) {
            als[row * HEADS + h0] = ps;
            ald[row * HEADS + h0] = pd;
        }
    }
}

// Layer-1 aggregation: one wave per dst node, 2 ch/lane (__half2 gather).
// 8-wide software pipeline (24 loads in flight per wave); fp32 accumulate.
__global__ void gat_agg_l1(const __half* __restrict__ h, const float* __restrict__ ex_t,
                           const float* __restrict__ bias,
                           const int* __restrict__ off, const int2* __restrict__ csr_sd,
                           float* __restrict__ out, int n, int ET) {
    constexpr int P = 8;
    int wid = (blockIdx.x * blockDim.x + threadIdx.x) >> 6;
    int lane = threadIdx.x & 63;
    if (wid >= n) return;
    const int hd = lane >> 4;
    const __half2* h2 = (const __half2*)h + lane;  // row stride = 64 half2
    const float* exp_ = ex_t + (size_t)hd * ET;
    int e0 = off[wid], e1 = off[wid + 1];
    float Sx = 0.f, Sy = 0.f, D = 0.f;

    float ex[P];
    __half2 hv[P];
#pragma unroll
    for (int p = 0; p < P; ++p) {
        int ee = e0 + p;
        int ie = (ee < e1) ? ee : e1 - 1;
        int s = csr_sd[ie].x;
        float exv = exp_[ie];
        ex[p] = (ee < e1) ? exv : 0.f;
        hv[p] = h2[(size_t)s * 64];
    }
    int e = e0;
    for (; e + P < e1; e += P) {
        float nex[P];
        __half2 nhv[P];
#pragma unroll
        for (int p = 0; p < P; ++p) {
            int ee = e + P + p;
            int ie = (ee < e1) ? ee : e1 - 1;
            int s = csr_sd[ie].x;
            float exv = exp_[ie];
            nex[p] = (ee < e1) ? exv : 0.f;
            nhv[p] = h2[(size_t)s * 64];
        }
#pragma unroll
        for (int p = 0; p < P; ++p) {
            D += ex[p];
            Sx = fmaf(ex[p], __low2float(hv[p]), Sx);
            Sy = fmaf(ex[p], __high2float(hv[p]), Sy);
            ex[p] = nex[p];
            hv[p] = nhv[p];
        }
    }
#pragma unroll
    for (int p = 0; p < P; ++p) {
        D += ex[p];
        Sx = fmaf(ex[p], __low2float(hv[p]), Sx);
        Sy = fmaf(ex[p], __high2float(hv[p]), Sy);
    }

    float inv = 1.f / D;
    float2 bv = ((const float2*)bias)[lane];
    float vx = Sx * inv + bv.x, vy = Sy * inv + bv.y;
    vx = vx > 0.f ? vx : (__expf(vx) - 1.f);
    vy = vy > 0.f ? vy : (__expf(vy) - 1.f);
    float2 o; o.x = vx; o.y = vy;
    ((float2*)out)[(size_t)wid * 64 + lane] = o;
}

// Layer-2 aggregation (C=64, fp16 h): 8-wide pipeline, 1 ch/lane, fused
// layer-3 feature head (h3 = elu(agg+b2) . W3, plus its logit terms).
__global__ void gat_agg_l2(const __half* __restrict__ h, const float* __restrict__ ex_t,
                           const float* __restrict__ bias,
                           const int* __restrict__ off, const int2* __restrict__ csr_sd,
                           const float* __restrict__ W3, const float* __restrict__ as3,
                           const float* __restrict__ ad3, float* __restrict__ h3,
                           float* __restrict__ als3, float* __restrict__ ald3,
                           int n, int ET) {
    constexpr int P = 8;
    int wid = (blockIdx.x * blockDim.x + threadIdx.x) >> 6;
    int lane = threadIdx.x & 63;
    if (wid >= n) return;
    const int hd = lane >> 5;
    const __half* hp = h + lane;
    const float* exp_ = ex_t + (size_t)hd * ET;
    int e0 = off[wid], e1 = off[wid + 1];
    float S = 0.f, D = 0.f;

    float ex[P];
    __half hv[P];
#pragma unroll
    for (int p = 0; p < P; ++p) {
        int ee = e0 + p;
        int ie = (ee < e1) ? ee : e1 - 1;
        int s = csr_sd[ie].x;
        float exv = exp_[ie];
        ex[p] = (ee < e1) ? exv : 0.f;
        hv[p] = hp[(size_t)s * 64];
    }
    int e = e0;
    for (; e + P < e1; e += P) {
        float nex[P];
        __half nhv[P];
#pragma unroll
        for (int p = 0; p < P; ++p) {
            int ee = e + P + p;
            int ie = (ee < e1) ? ee : e1 - 1;
            int s = csr_sd[ie].x;
            float exv = exp_[ie];
            nex[p] = (ee < e1) ? exv : 0.f;
            nhv[p] = hp[(size_t)s * 64];
        }
#pragma unroll
        for (int p = 0; p < P; ++p) {
            D += ex[p];
            S = fmaf(ex[p], __half2float(hv[p]), S);
            ex[p] = nex[p];
            hv[p] = nhv[p];
        }
    }
#pragma unroll
    for (int p = 0; p < P; ++p) {
        D += ex[p];
        S = fmaf(ex[p], __half2float(hv[p]), S);
    }

    float v = S / D + bias[lane];
    v = v > 0.f ? v : (__expf(v) - 1.f);     // a2[wid][lane]
    float r = v * W3[lane];
#pragma unroll
    for (int msk = 1; msk < 64; msk <<= 1) r += __shfl_xor(r, msk, 64);
    if (lane == 0) {
        h3[wid] = r;
        als3[wid] = r * as3[0];
        ald3[wid] = r * ad3[0];
    }
}

// Layer-3 aggregation: scalar channel, thread per node, 2-wide pipeline.
__global__ void gat_agg1(const float* __restrict__ h, const float* __restrict__ ex_t,
                         const float* __restrict__ bias,
                         const int* __restrict__ off, const int2* __restrict__ csr_sd,
                         float* __restrict__ out, int n) {
    int i = blockIdx.x * blockDim.x + threadIdx.x;
    if (i >= n) return;
    int e0 = off[i], e1 = off[i + 1];
    float S = 0.f, D = 0.f;
    float ex[2], hv[2];
#pragma unroll
    for (int p = 0; p < 2; ++p) {
        int ee = e0 + p;
        int ie = (ee < e1) ? ee : e1 - 1;
        int s = csr_sd[ie].x;
        float exv = ex_t[ie];
        ex[p] = (ee < e1) ? exv : 0.f;
        hv[p] = h[s];
    }
    int e = e0;
    for (; e + 2 < e1; e += 2) {
#pragma unroll
        for (int p = 0; p < 2; ++p) {
            int ee = e + 2 + p;
            int ie = (ee < e1) ? ee : e1 - 1;
            int s = csr_sd[ie].x;
            float exv = ex_t[ie];
            float nex = (ee < e1) ? exv : 0.f;
            float nhv = h[s];
            D += ex[p];
            S = fmaf(ex[p], hv[p], S);
            ex[p] = nex;
            hv[p] = nhv;
        }
    }
#pragma unroll
    for (int p = 0; p < 2; ++p) {
        D += ex[p];
        S = fmaf(ex[p], hv[p], S);
    }
    out[i] = S / D + bias[0];
}

extern "C" void kernel_launch(void* const* d_in, const int* in_sizes, int n_in,
                              void* d_out, int out_size, void* d_ws, size_t ws_size,
                              hipStream_t stream) {
    const float* x   = (const float*)d_in[0];
    const int*   ei  = (const int*)d_in[1];
    const float* W1  = (const float*)d_in[2];
    const float* as1 = (const float*)d_in[3];
    const float* ad1 = (const float*)d_in[4];
    const float* b1  = (const float*)d_in[5];
    const float* W2  = (const float*)d_in[6];
    const float* as2 = (const float*)d_in[7];
    const float* ad2 = (const float*)d_in[8];
    const float* b2  = (const float*)d_in[9];
    const float* W3  = (const float*)d_in[10];
    const float* as3 = (const float*)d_in[11];
    const float* ad3 = (const float*)d_in[12];
    const float* b3  = (const float*)d_in[13];
    float* out = (float*)d_out;

    const int N = in_sizes[0] / F_IN;  // 50000
    const int E = in_sizes[1] / 2;     // 800000
    const int ET = E + N;

    char* w = (char*)d_ws;
    size_t o = 0;
    auto alloc = [&](size_t bytes) -> void* {
        void* p = w + o;
        o += (bytes + 255) & ~(size_t)255;
        return p;
    };
    __half* hbuf = (__half*)alloc((size_t)N * 128 * 2);  // h1; reused as h2
    float* a1   = (float*)alloc((size_t)N * 128 * 4);
    float* h3   = (float*)alloc((size_t)N * 4);
    float* als  = (float*)alloc((size_t)N * 4 * 4);
    float* ald  = (float*)alloc((size_t)N * 4 * 4);
    float* als3 = (float*)alloc((size_t)N * 4);
    float* ald3 = (float*)alloc((size_t)N * 4);
    int* deg    = (int*)alloc((size_t)(N + 1) * 4);
    int* off    = (int*)alloc((size_t)(N + 1) * 4);
    int* cursor = (int*)alloc((size_t)N * 4);
    int* bsums  = (int*)alloc(1024);
    int2* csr_sd = (int2*)alloc((size_t)ET * 8);
    float* exb  = (float*)alloc((size_t)4 * ET * 4);   // reused per layer

    __half* h2 = hbuf;              // h1 dead after agg_l1

    const int* esrc = ei;
    const int* edst = ei + E;

    // ---- CSR build (dst-sorted incoming-edge lists, int2{src,dst} per slot) ----
    zero_int<<<(N + 1 + 255) / 256, 256, 0, stream>>>(deg, N + 1);
    count_deg4<<<((E + 3) / 4 + 255) / 256, 256, 0, stream>>>(edst, deg, E);
    int n1 = N + 1;
    int nb = (n1 + SB - 1) / SB;
    scan1<<<nb, SB, 0, stream>>>(deg, off, bsums, n1, N);   // +1 self-loop each
    scan2<<<1, SB, 0, stream>>>(bsums, nb);
    scan3<<<nb, SB, 0, stream>>>(off, cursor, bsums, n1, N);
    {
        int E4 = (E + 3) >> 2;
        scatter_csr4<<<(E4 + N + 255) / 256, 256, 0, stream>>>(
            esrc, edst, cursor, csr_sd, E, N);
    }

    const int gblk = (N + 127) / 128;
    const int eblk = (ET + 255) / 256;

    // ---- Layer 1: 128 -> 4 heads x 32, concat, ELU ----
    gemm_fused<128, 8, 4><<<gblk, dim3(16, 32), 0, stream>>>(
        x, W1, as1, ad1, hbuf, als, ald, N);
    edge_ex<4><<<eblk, 256, 0, stream>>>(als, ald, csr_sd, exb, ET);
    gat_agg_l1<<<(N * 64 + 255) / 256, 256, 0, stream>>>(
        hbuf, exb, b1, off, csr_sd, a1, N, ET);

    // ---- Layer 2: 128 -> 2 heads x 32, concat, ELU (+ fused layer-3 head) ----
    gemm_fused<64, 4, 2><<<gblk, dim3(16, 32), 0, stream>>>(
        a1, W2, as2, ad2, h2, als, ald, N);
    edge_ex<2><<<eblk, 256, 0, stream>>>(als, ald, csr_sd, exb, ET);
    gat_agg_l2<<<(N * 64 + 255) / 256, 256, 0, stream>>>(
        h2, exb, b2, off, csr_sd, W3, as3, ad3, h3, als3, ald3, N, ET);

    // ---- Layer 3: aggregation of scalar feature ----
    edge_ex<1><<<eblk, 256, 0, stream>>>(als3, ald3, csr_sd, exb, ET);
    gat_agg1<<<(N + 255) / 256, 256, 0, stream>>>(h3, exb, b3, off, csr_sd, out, N);
}

// Round 9
// 229.265 us; speedup vs baseline: 1.3134x; 1.1043x over previous
//
#include <hip/hip_runtime.h>
#include <hip/hip_fp16.h>
#include <math.h>

#define F_IN 128
constexpr int SB = 256;

__global__ void zero_int(int* p, int n) {
    int i = blockIdx.x * 256 + threadIdx.x;
    if (i < n) p[i] = 0;
}

// 4 edges/thread, int4 loads, fire-and-forget atomics (self-loops folded into scan).
__global__ void count_deg4(const int* __restrict__ dst, int* __restrict__ deg, int E) {
    int t = blockIdx.x * 256 + threadIdx.x;
    int base = t * 4;
    if (base + 3 < E) {
        int4 d = *(const int4*)(dst + base);
        atomicAdd(&deg[d.x], 1);
        atomicAdd(&deg[d.y], 1);
        atomicAdd(&deg[d.z], 1);
        atomicAdd(&deg[d.w], 1);
    } else {
        for (int k = 0; k < 4; ++k) {
            int e = base + k;
            if (e < E) atomicAdd(&deg[dst[e]], 1);
        }
    }
}

// 3-kernel exclusive scan; +1 per element for i<selfN (self-loops)
__global__ void scan1(const int* __restrict__ in, int* __restrict__ out,
                      int* __restrict__ bsums, int n, int selfN) {
    __shared__ int sm[SB];
    int i = blockIdx.x * SB + threadIdx.x;
    int v = (i < n) ? (in[i] + (i < selfN ? 1 : 0)) : 0;
    sm[threadIdx.x] = v;
    __syncthreads();
    for (int d = 1; d < SB; d <<= 1) {
        int t = (threadIdx.x >= d) ? sm[threadIdx.x - d] : 0;
        __syncthreads();
        sm[threadIdx.x] += t;
        __syncthreads();
    }
    if (i < n) out[i] = sm[threadIdx.x] - v;
    if (threadIdx.x == SB - 1) bsums[blockIdx.x] = sm[SB - 1];
}

__global__ void scan2(int* __restrict__ bsums, int nb) {
    __shared__ int sm[SB];
    int v = (threadIdx.x < nb) ? bsums[threadIdx.x] : 0;
    sm[threadIdx.x] = v;
    __syncthreads();
    for (int d = 1; d < SB; d <<= 1) {
        int t = (threadIdx.x >= d) ? sm[threadIdx.x - d] : 0;
        __syncthreads();
        sm[threadIdx.x] += t;
        __syncthreads();
    }
    if (threadIdx.x < nb) bsums[threadIdx.x] = sm[threadIdx.x] - v;
}

__global__ void scan3(int* __restrict__ off, int* __restrict__ cursor,
                      const int* __restrict__ bsums, int n, int ncur) {
    int i = blockIdx.x * SB + threadIdx.x;
    if (i < n) {
        int v = off[i] + bsums[blockIdx.x];
        off[i] = v;
        if (i < ncur) cursor[i] = v;
    }
}

// GEMM body as device fn so it can be fused with the scatter.
// C_half[M,BN] = A[M,128]*B[128,BN], fused fp32 attention-logit epilogue.
template <int BN, int TN, int HEADS>
__device__ __forceinline__ void gemm_dev(
    const float* __restrict__ A, const float* __restrict__ B,
    const float* __restrict__ asrc, const float* __restrict__ adst,
    __half* __restrict__ C, float* __restrict__ als, float* __restrict__ ald,
    int M, int bid) {
    constexpr int BM = 128, BK = 16, TM = 4, K = 128, OC = 32;
    constexpr int GROUP = OC / TN;
    __shared__ float As[BK][BM + 4];
    __shared__ float Bs[BK][BN];
    const int tx = threadIdx.x, ty = threadIdx.y;
    const int tid = ty * 16 + tx;
    const int row0 = bid * BM;
    const int i0 = ty * TM;
    const int j0 = tx * TN;

    float acc[TM][TN];
#pragma unroll
    for (int m = 0; m < TM; ++m)
#pragma unroll
        for (int n = 0; n < TN; ++n) acc[m][n] = 0.f;

    const int ar = tid >> 2;
    const int ak = (tid & 3) * 4;
    int arow = row0 + ar;
    if (arow >= M) arow = M - 1;
    const float* Aptr = A + (size_t)arow * K + ak;
    const int bk = (BN == 128) ? (tid >> 5) : (tid >> 4);
    const int bc = (BN == 128) ? ((tid & 31) * 4) : ((tid & 15) * 4);
    const bool bact = (BN == 128) || (tid < 256);

    for (int kc = 0; kc < K; kc += BK) {
        float4 av = *(const float4*)(Aptr + kc);
        float4 bv;
        if (bact) bv = *(const float4*)(B + (size_t)(kc + bk) * BN + bc);
        __syncthreads();
        As[ak + 0][ar] = av.x;
        As[ak + 1][ar] = av.y;
        As[ak + 2][ar] = av.z;
        As[ak + 3][ar] = av.w;
        if (bact) *(float4*)&Bs[bk][bc] = bv;
        __syncthreads();
#pragma unroll
        for (int kk = 0; kk < BK; ++kk) {
            float4 a4 = *(const float4*)&As[kk][i0];
            float arr[TM] = {a4.x, a4.y, a4.z, a4.w};
            float br[TN];
            float4 b0 = *(const float4*)&Bs[kk][j0];
            br[0] = b0.x; br[1] = b0.y; br[2] = b0.z; br[3] = b0.w;
            if constexpr (TN == 8) {
                float4 b1 = *(const float4*)&Bs[kk][j0 + 4];
                br[4] = b1.x; br[5] = b1.y; br[6] = b1.z; br[7] = b1.w;
            }
#pragma unroll
            for (int m = 0; m < TM; ++m)
#pragma unroll
                for (int n = 0; n < TN; ++n) acc[m][n] += arr[m] * br[n];
        }
    }

    const int h0 = j0 / OC;
#pragma unroll
    for (int m = 0; m < TM; ++m) {
        int row = row0 + i0 + m;
        bool ok = row < M;
        if (ok) {
            alignas(16) __half2 ph[TN / 2];
#pragma unroll
            for (int n2 = 0; n2 < TN / 2; ++n2)
                ph[n2] = __floats2half2_rn(acc[m][2 * n2], acc[m][2 * n2 + 1]);
            if constexpr (TN == 8)
                *(uint4*)&C[(size_t)row * BN + j0] = *(uint4*)ph;
            else
                *(uint2*)&C[(size_t)row * BN + j0] = *(uint2*)ph;
        }
        float ps = 0.f, pd = 0.f;
#pragma unroll
        for (int n = 0; n < TN; ++n) {
            ps += acc[m][n] * asrc[j0 + n];
            pd += acc[m][n] * adst[j0 + n];
        }
#pragma unroll
        for (int msk = 1; msk < GROUP; msk <<= 1) {
            ps += __shfl_xor(ps, msk, 64);
            pd += __shfl_xor(pd, msk, 64);
        }
        if (ok && (tx & (GROUP - 1)) == 0) {
            als[row * HEADS + h0] = ps;
            ald[row * HEADS + h0] = pd;
        }
    }
}

// Fused: blocks [0,gblk) run layer-1 GEMM; the rest run the CSR scatter
// (4B src-only payload -> half the cross-XCD false-sharing writeback).
__global__ __launch_bounds__(512) void gemm1_scatter(
    const float* __restrict__ A, const float* __restrict__ B,
    const float* __restrict__ asrc, const float* __restrict__ adst,
    __half* __restrict__ C, float* __restrict__ als, float* __restrict__ ald,
    int M, int gblk,
    const int* __restrict__ src, const int* __restrict__ dst,
    int* __restrict__ cursor, int* __restrict__ csr, int E, int N) {
    if ((int)blockIdx.x < gblk) {
        gemm_dev<128, 8, 4>(A, B, asrc, adst, C, als, ald, M, blockIdx.x);
        return;
    }
    int tid = threadIdx.y * 16 + threadIdx.x;
    int t = (blockIdx.x - gblk) * 512 + tid;
    int E4 = (E + 3) >> 2;
    if (t < E4) {
        int base = t * 4;
        if (base + 3 < E) {
            int4 s4 = *(const int4*)(src + base);
            int4 d4 = *(const int4*)(dst + base);
            int p0 = atomicAdd(&cursor[d4.x], 1);
            int p1 = atomicAdd(&cursor[d4.y], 1);
            int p2 = atomicAdd(&cursor[d4.z], 1);
            int p3 = atomicAdd(&cursor[d4.w], 1);
            csr[p0] = s4.x;
            csr[p1] = s4.y;
            csr[p2] = s4.z;
            csr[p3] = s4.w;
        } else {
            for (int k = 0; k < 4; ++k) {
                int e = base + k;
                if (e < E) {
                    int s = src[e], d = dst[e];
                    int p = atomicAdd(&cursor[d], 1);
                    csr[p] = s;
                }
            }
        }
    } else {
        int i = t - E4;
        if (i < N) {
            int p = atomicAdd(&cursor[i], 1);
            csr[p] = i;
        }
    }
}

// Layer-2 GEMM (standalone)
template <int BN, int TN, int HEADS>
__global__ __launch_bounds__(512) void gemm_fused(
    const float* __restrict__ A, const float* __restrict__ B,
    const float* __restrict__ asrc, const float* __restrict__ adst,
    __half* __restrict__ C, float* __restrict__ als, float* __restrict__ ald,
    int M) {
    gemm_dev<BN, TN, HEADS>(A, B, asrc, adst, C, als, ald, M, blockIdx.x);
}

// Node-parallel per-slot softmax numerators: 16 lanes walk one node's slots.
// dst == node (uniform), so only als[src] is gathered; csr_dst not needed.
template <int HEADS>
__global__ void edge_ex_node(const float* __restrict__ als, const float* __restrict__ ald,
                             const int* __restrict__ csr, const int* __restrict__ off,
                             float* __restrict__ ex_t, int n, int ET) {
    int g = blockIdx.x * blockDim.x + threadIdx.x;
    int node = g >> 4;
    int lane = g & 15;
    if (node >= n) return;
    float ad[HEADS];
    if constexpr (HEADS == 4) {
        float4 a = ((const float4*)ald)[node];
        ad[0] = a.x; ad[1] = a.y; ad[2] = a.z; ad[3] = a.w;
    } else if constexpr (HEADS == 2) {
        float2 a = ((const float2*)ald)[node];
        ad[0] = a.x; ad[1] = a.y;
    } else {
        ad[0] = ald[node];
    }
    int e1 = off[node + 1];
    for (int e = off[node] + lane; e < e1; e += 16) {
        int s = csr[e];
        float av[HEADS];
        if constexpr (HEADS == 4) {
            float4 a = ((const float4*)als)[s];
            av[0] = a.x; av[1] = a.y; av[2] = a.z; av[3] = a.w;
        } else if constexpr (HEADS == 2) {
            float2 a = ((const float2*)als)[s];
            av[0] = a.x; av[1] = a.y;
        } else {
            av[0] = als[s];
        }
#pragma unroll
        for (int hd = 0; hd < HEADS; ++hd) {
            float lg = av[hd] + ad[hd];
            lg = lg > 0.f ? lg : 0.2f * lg;
            ex_t[(size_t)hd * ET + e] = __expf(lg);
        }
    }
}

// Layer-1 aggregation: one wave per dst node, 2 ch/lane (__half2 gather),
// 8-wide software pipeline, fp32 accumulate.
__global__ void gat_agg_l1(const __half* __restrict__ h, const float* __restrict__ ex_t,
                           const float* __restrict__ bias,
                           const int* __restrict__ off, const int* __restrict__ csr,
                           float* __restrict__ out, int n, int ET) {
    constexpr int P = 8;
    int wid = (blockIdx.x * blockDim.x + threadIdx.x) >> 6;
    int lane = threadIdx.x & 63;
    if (wid >= n) return;
    const int hd = lane >> 4;
    const __half2* h2 = (const __half2*)h + lane;
    const float* exp_ = ex_t + (size_t)hd * ET;
    int e0 = off[wid], e1 = off[wid + 1];
    float Sx = 0.f, Sy = 0.f, D = 0.f;

    float ex[P];
    __half2 hv[P];
#pragma unroll
    for (int p = 0; p < P; ++p) {
        int ee = e0 + p;
        int ie = (ee < e1) ? ee : e1 - 1;
        int s = csr[ie];
        float exv = exp_[ie];
        ex[p] = (ee < e1) ? exv : 0.f;
        hv[p] = h2[(size_t)s * 64];
    }
    int e = e0;
    for (; e + P < e1; e += P) {
        float nex[P];
        __half2 nhv[P];
#pragma unroll
        for (int p = 0; p < P; ++p) {
            int ee = e + P + p;
            int ie = (ee < e1) ? ee : e1 - 1;
            int s = csr[ie];
            float exv = exp_[ie];
            nex[p] = (ee < e1) ? exv : 0.f;
            nhv[p] = h2[(size_t)s * 64];
        }
#pragma unroll
        for (int p = 0; p < P; ++p) {
            D += ex[p];
            Sx = fmaf(ex[p], __low2float(hv[p]), Sx);
            Sy = fmaf(ex[p], __high2float(hv[p]), Sy);
            ex[p] = nex[p];
            hv[p] = nhv[p];
        }
    }
#pragma unroll
    for (int p = 0; p < P; ++p) {
        D += ex[p];
        Sx = fmaf(ex[p], __low2float(hv[p]), Sx);
        Sy = fmaf(ex[p], __high2float(hv[p]), Sy);
    }

    float inv = 1.f / D;
    float2 bv = ((const float2*)bias)[lane];
    float vx = Sx * inv + bv.x, vy = Sy * inv + bv.y;
    vx = vx > 0.f ? vx : (__expf(vx) - 1.f);
    vy = vy > 0.f ? vy : (__expf(vy) - 1.f);
    float2 o; o.x = vx; o.y = vy;
    ((float2*)out)[(size_t)wid * 64 + lane] = o;
}

// Layer-2 aggregation (C=64, fp16 h): 8-wide pipeline, 1 ch/lane, fused
// layer-3 feature head (h3 = elu(agg+b2) . W3, plus its logit terms).
__global__ void gat_agg_l2(const __half* __restrict__ h, const float* __restrict__ ex_t,
                           const float* __restrict__ bias,
                           const int* __restrict__ off, const int* __restrict__ csr,
                           const float* __restrict__ W3, const float* __restrict__ as3,
                           const float* __restrict__ ad3, float* __restrict__ h3,
                           float* __restrict__ als3, float* __restrict__ ald3,
                           int n, int ET) {
    constexpr int P = 8;
    int wid = (blockIdx.x * blockDim.x + threadIdx.x) >> 6;
    int lane = threadIdx.x & 63;
    if (wid >= n) return;
    const int hd = lane >> 5;
    const __half* hp = h + lane;
    const float* exp_ = ex_t + (size_t)hd * ET;
    int e0 = off[wid], e1 = off[wid + 1];
    float S = 0.f, D = 0.f;

    float ex[P];
    __half hv[P];
#pragma unroll
    for (int p = 0; p < P; ++p) {
        int ee = e0 + p;
        int ie = (ee < e1) ? ee : e1 - 1;
        int s = csr[ie];
        float exv = exp_[ie];
        ex[p] = (ee < e1) ? exv : 0.f;
        hv[p] = hp[(size_t)s * 64];
    }
    int e = e0;
    for (; e + P < e1; e += P) {
        float nex[P];
        __half nhv[P];
#pragma unroll
        for (int p = 0; p < P; ++p) {
            int ee = e + P + p;
            int ie = (ee < e1) ? ee : e1 - 1;
            int s = csr[ie];
            float exv = exp_[ie];
            nex[p] = (ee < e1) ? exv : 0.f;
            nhv[p] = hp[(size_t)s * 64];
        }
#pragma unroll
        for (int p = 0; p < P; ++p) {
            D += ex[p];
            S = fmaf(ex[p], __half2float(hv[p]), S);
            ex[p] = nex[p];
            hv[p] = nhv[p];
        }
    }
#pragma unroll
    for (int p = 0; p < P; ++p) {
        D += ex[p];
        S = fmaf(ex[p], __half2float(hv[p]), S);
    }

    float v = S / D + bias[lane];
    v = v > 0.f ? v : (__expf(v) - 1.f);     // a2[wid][lane]
    float r = v * W3[lane];
#pragma unroll
    for (int msk = 1; msk < 64; msk <<= 1) r += __shfl_xor(r, msk, 64);
    if (lane == 0) {
        h3[wid] = r;
        als3[wid] = r * as3[0];
        ald3[wid] = r * ad3[0];
    }
}

// Layer-3 aggregation: scalar channel, thread per node, 2-wide pipeline.
__global__ void gat_agg1(const float* __restrict__ h, const float* __restrict__ ex_t,
                         const float* __restrict__ bias,
                         const int* __restrict__ off, const int* __restrict__ csr,
                         float* __restrict__ out, int n) {
    int i = blockIdx.x * blockDim.x + threadIdx.x;
    if (i >= n) return;
    int e0 = off[i], e1 = off[i + 1];
    float S = 0.f, D = 0.f;
    float ex[2], hv[2];
#pragma unroll
    for (int p = 0; p < 2; ++p) {
        int ee = e0 + p;
        int ie = (ee < e1) ? ee : e1 - 1;
        int s = csr[ie];
        float exv = ex_t[ie];
        ex[p] = (ee < e1) ? exv : 0.f;
        hv[p] = h[s];
    }
    int e = e0;
    for (; e + 2 < e1; e += 2) {
#pragma unroll
        for (int p = 0; p < 2; ++p) {
            int ee = e + 2 + p;
            int ie = (ee < e1) ? ee : e1 - 1;
            int s = csr[ie];
            float exv = ex_t[ie];
            float nex = (ee < e1) ? exv : 0.f;
            float nhv = h[s];
            D += ex[p];
            S = fmaf(ex[p], hv[p], S);
            ex[p] = nex;
            hv[p] = nhv;
        }
    }
#pragma unroll
    for (int p = 0; p < 2; ++p) {
        D += ex[p];
        S = fmaf(ex[p], hv[p], S);
    }
    out[i] = S / D + bias[0];
}

extern "C" void kernel_launch(void* const* d_in, const int* in_sizes, int n_in,
                              void* d_out, int out_size, void* d_ws, size_t ws_size,
                              hipStream_t stream) {
    const float* x   = (const float*)d_in[0];
    const int*   ei  = (const int*)d_in[1];
    const float* W1  = (const float*)d_in[2];
    const float* as1 = (const float*)d_in[3];
    const float* ad1 = (const float*)d_in[4];
    const float* b1  = (const float*)d_in[5];
    const float* W2  = (const float*)d_in[6];
    const float* as2 = (const float*)d_in[7];
    const float* ad2 = (const float*)d_in[8];
    const float* b2  = (const float*)d_in[9];
    const float* W3  = (const float*)d_in[10];
    const float* as3 = (const float*)d_in[11];
    const float* ad3 = (const float*)d_in[12];
    const float* b3  = (const float*)d_in[13];
    float* out = (float*)d_out;

    const int N = in_sizes[0] / F_IN;  // 50000
    const int E = in_sizes[1] / 2;     // 800000
    const int ET = E + N;

    char* w = (char*)d_ws;
    size_t o = 0;
    auto alloc = [&](size_t bytes) -> void* {
        void* p = w + o;
        o += (bytes + 255) & ~(size_t)255;
        return p;
    };
    __half* hbuf = (__half*)alloc((size_t)N * 128 * 2);  // h1; reused as h2
    float* a1   = (float*)alloc((size_t)N * 128 * 4);
    float* h3   = (float*)alloc((size_t)N * 4);
    float* als  = (float*)alloc((size_t)N * 4 * 4);
    float* ald  = (float*)alloc((size_t)N * 4 * 4);
    float* als3 = (float*)alloc((size_t)N * 4);
    float* ald3 = (float*)alloc((size_t)N * 4);
    int* deg    = (int*)alloc((size_t)(N + 1) * 4);
    int* off    = (int*)alloc((size_t)(N + 1) * 4);
    int* cursor = (int*)alloc((size_t)N * 4);
    int* bsums  = (int*)alloc(1024);
    int* csr    = (int*)alloc((size_t)ET * 4);
    float* exb  = (float*)alloc((size_t)4 * ET * 4);   // reused per layer

    __half* h2 = hbuf;              // h1 dead after agg_l1

    const int* esrc = ei;
    const int* edst = ei + E;

    // ---- CSR offsets ----
    zero_int<<<(N + 1 + 255) / 256, 256, 0, stream>>>(deg, N + 1);
    count_deg4<<<((E + 3) / 4 + 255) / 256, 256, 0, stream>>>(edst, deg, E);
    int n1 = N + 1;
    int nb = (n1 + SB - 1) / SB;
    scan1<<<nb, SB, 0, stream>>>(deg, off, bsums, n1, N);   // +1 self-loop each
    scan2<<<1, SB, 0, stream>>>(bsums, nb);
    scan3<<<nb, SB, 0, stream>>>(off, cursor, bsums, n1, N);

    const int gblk = (N + 127) / 128;

    // ---- Layer-1 GEMM fused with CSR scatter (independent work, overlapped) ----
    {
        int E4 = (E + 3) >> 2;
        int sblk = (E4 + N + 511) / 512;
        gemm1_scatter<<<gblk + sblk, dim3(16, 32), 0, stream>>>(
            x, W1, as1, ad1, hbuf, als, ald, N, gblk,
            esrc, edst, cursor, csr, E, N);
    }

    const int exblk = (N * 16 + 255) / 256;

    // ---- Layer 1 softmax + aggregation ----
    edge_ex_node<4><<<exblk, 256, 0, stream>>>(als, ald, csr, off, exb, N, ET);
    gat_agg_l1<<<(N * 64 + 255) / 256, 256, 0, stream>>>(
        hbuf, exb, b1, off, csr, a1, N, ET);

    // ---- Layer 2: 128 -> 2 heads x 32, concat, ELU (+ fused layer-3 head) ----
    gemm_fused<64, 4, 2><<<gblk, dim3(16, 32), 0, stream>>>(
        a1, W2, as2, ad2, h2, als, ald, N);
    edge_ex_node<2><<<exblk, 256, 0, stream>>>(als, ald, csr, off, exb, N, ET);
    gat_agg_l2<<<(N * 64 + 255) / 256, 256, 0, stream>>>(
        h2, exb, b2, off, csr, W3, as3, ad3, h3, als3, ald3, N, ET);

    // ---- Layer 3: aggregation of scalar feature ----
    edge_ex_node<1><<<exblk, 256, 0, stream>>>(als3, ald3, csr, off, exb, N, ET);
    gat_agg1<<<(N + 255) / 256, 256, 0, stream>>>(h3, exb, b3, off, csr, out, N);
}

// Round 10
// 219.459 us; speedup vs baseline: 1.3721x; 1.0447x over previous
//
#include <hip/hip_runtime.h>
#include <hip/hip_fp16.h>
#include <math.h>

#define F_IN 128
constexpr int SB = 256;

__global__ void zero_int(int* p, int n) {
    int i = blockIdx.x * 256 + threadIdx.x;
    if (i < n) p[i] = 0;
}

// 4 edges/thread, int4 loads, fire-and-forget atomics (self-loops folded into scan).
__global__ void count_deg4(const int* __restrict__ dst, int* __restrict__ deg, int E) {
    int t = blockIdx.x * 256 + threadIdx.x;
    int base = t * 4;
    if (base + 3 < E) {
        int4 d = *(const int4*)(dst + base);
        atomicAdd(&deg[d.x], 1);
        atomicAdd(&deg[d.y], 1);
        atomicAdd(&deg[d.z], 1);
        atomicAdd(&deg[d.w], 1);
    } else {
        for (int k = 0; k < 4; ++k) {
            int e = base + k;
            if (e < E) atomicAdd(&deg[dst[e]], 1);
        }
    }
}

// 3-kernel exclusive scan; +1 per element for i<selfN (self-loops)
__global__ void scan1(const int* __restrict__ in, int* __restrict__ out,
                      int* __restrict__ bsums, int n, int selfN) {
    __shared__ int sm[SB];
    int i = blockIdx.x * SB + threadIdx.x;
    int v = (i < n) ? (in[i] + (i < selfN ? 1 : 0)) : 0;
    sm[threadIdx.x] = v;
    __syncthreads();
    for (int d = 1; d < SB; d <<= 1) {
        int t = (threadIdx.x >= d) ? sm[threadIdx.x - d] : 0;
        __syncthreads();
        sm[threadIdx.x] += t;
        __syncthreads();
    }
    if (i < n) out[i] = sm[threadIdx.x] - v;
    if (threadIdx.x == SB - 1) bsums[blockIdx.x] = sm[SB - 1];
}

__global__ void scan2(int* __restrict__ bsums, int nb) {
    __shared__ int sm[SB];
    int v = (threadIdx.x < nb) ? bsums[threadIdx.x] : 0;
    sm[threadIdx.x] = v;
    __syncthreads();
    for (int d = 1; d < SB; d <<= 1) {
        int t = (threadIdx.x >= d) ? sm[threadIdx.x - d] : 0;
        __syncthreads();
        sm[threadIdx.x] += t;
        __syncthreads();
    }
    if (threadIdx.x < nb) bsums[threadIdx.x] = sm[threadIdx.x] - v;
}

__global__ void scan3(int* __restrict__ off, int* __restrict__ cursor,
                      const int* __restrict__ bsums, int n, int ncur) {
    int i = blockIdx.x * SB + threadIdx.x;
    if (i < n) {
        int v = off[i] + bsums[blockIdx.x];
        off[i] = v;
        if (i < ncur) cursor[i] = v;
    }
}

// GEMM body as device fn so it can be fused with the scatter.
// C_half[M,BN] = A[M,128]*B[128,BN], fused fp32 attention-logit epilogue.
// TN==8: columns remapped to chunks {tx*4, 64+tx*4} -> 2-way LDS aliasing (free)
// instead of the 4-way conflict of j0=tx*8.
template <int BN, int TN, int HEADS>
__device__ __forceinline__ void gemm_dev(
    const float* __restrict__ A, const float* __restrict__ B,
    const float* __restrict__ asrc, const float* __restrict__ adst,
    __half* __restrict__ C, float* __restrict__ als, float* __restrict__ ald,
    int M, int bid) {
    constexpr int BM = 128, BK = 16, TM = 4, K = 128, OC = 32;
    __shared__ float As[BK][BM + 4];
    __shared__ float Bs[BK][BN];
    const int tx = threadIdx.x, ty = threadIdx.y;
    const int tid = ty * 16 + tx;
    const int row0 = bid * BM;
    const int i0 = ty * TM;
    const int j0a = tx * 4;           // chunk A columns
    const int j0b = 64 + tx * 4;      // chunk B columns (TN==8 only)

    float acc[TM][TN];
#pragma unroll
    for (int m = 0; m < TM; ++m)
#pragma unroll
        for (int n = 0; n < TN; ++n) acc[m][n] = 0.f;

    const int ar = tid >> 2;
    const int ak = (tid & 3) * 4;
    int arow = row0 + ar;
    if (arow >= M) arow = M - 1;
    const float* Aptr = A + (size_t)arow * K + ak;
    const int bk = (BN == 128) ? (tid >> 5) : (tid >> 4);
    const int bc = (BN == 128) ? ((tid & 31) * 4) : ((tid & 15) * 4);
    const bool bact = (BN == 128) || (tid < 256);

    for (int kc = 0; kc < K; kc += BK) {
        float4 av = *(const float4*)(Aptr + kc);
        float4 bv;
        if (bact) bv = *(const float4*)(B + (size_t)(kc + bk) * BN + bc);
        __syncthreads();
        As[ak + 0][ar] = av.x;
        As[ak + 1][ar] = av.y;
        As[ak + 2][ar] = av.z;
        As[ak + 3][ar] = av.w;
        if (bact) *(float4*)&Bs[bk][bc] = bv;
        __syncthreads();
#pragma unroll
        for (int kk = 0; kk < BK; ++kk) {
            float4 a4 = *(const float4*)&As[kk][i0];
            float arr[TM] = {a4.x, a4.y, a4.z, a4.w};
            float br[TN];
            float4 b0 = *(const float4*)&Bs[kk][j0a];
            br[0] = b0.x; br[1] = b0.y; br[2] = b0.z; br[3] = b0.w;
            if constexpr (TN == 8) {
                float4 b1 = *(const float4*)&Bs[kk][j0b];
                br[4] = b1.x; br[5] = b1.y; br[6] = b1.z; br[7] = b1.w;
            }
#pragma unroll
            for (int m = 0; m < TM; ++m)
#pragma unroll
                for (int n = 0; n < TN; ++n) acc[m][n] += arr[m] * br[n];
        }
    }

#pragma unroll
    for (int m = 0; m < TM; ++m) {
        int row = row0 + i0 + m;
        bool ok = row < M;
        if constexpr (TN == 8) {
            if (ok) {
                alignas(8) __half2 pa[2], pb[2];
#pragma unroll
                for (int n2 = 0; n2 < 2; ++n2) {
                    pa[n2] = __floats2half2_rn(acc[m][2 * n2], acc[m][2 * n2 + 1]);
                    pb[n2] = __floats2half2_rn(acc[m][4 + 2 * n2], acc[m][5 + 2 * n2]);
                }
                *(uint2*)&C[(size_t)row * BN + j0a] = *(uint2*)pa;
                *(uint2*)&C[(size_t)row * BN + j0b] = *(uint2*)pb;
            }
            // heads: chunk A -> hA = tx/8 (0,1); chunk B -> 2+hA
            float psA = 0.f, pdA = 0.f, psB = 0.f, pdB = 0.f;
#pragma unroll
            for (int n = 0; n < 4; ++n) {
                psA += acc[m][n] * asrc[j0a + n];
                pdA += acc[m][n] * adst[j0a + n];
                psB += acc[m][n + 4] * asrc[j0b + n];
                pdB += acc[m][n + 4] * adst[j0b + n];
            }
#pragma unroll
            for (int msk = 1; msk < 8; msk <<= 1) {
                psA += __shfl_xor(psA, msk, 64);
                pdA += __shfl_xor(pdA, msk, 64);
                psB += __shfl_xor(psB, msk, 64);
                pdB += __shfl_xor(pdB, msk, 64);
            }
            if (ok && (tx & 7) == 0) {
                int hA = tx >> 3;
                als[row * HEADS + hA] = psA;
                ald[row * HEADS + hA] = pdA;
                als[row * HEADS + 2 + hA] = psB;
                ald[row * HEADS + 2 + hA] = pdB;
            }
        } else {
            if (ok) {
                alignas(8) __half2 ph[2];
#pragma unroll
                for (int n2 = 0; n2 < 2; ++n2)
                    ph[n2] = __floats2half2_rn(acc[m][2 * n2], acc[m][2 * n2 + 1]);
                *(uint2*)&C[(size_t)row * BN + j0a] = *(uint2*)ph;
            }
            float ps = 0.f, pd = 0.f;
#pragma unroll
            for (int n = 0; n < TN; ++n) {
                ps += acc[m][n] * asrc[j0a + n];
                pd += acc[m][n] * adst[j0a + n];
            }
#pragma unroll
            for (int msk = 1; msk < 8; msk <<= 1) {
                ps += __shfl_xor(ps, msk, 64);
                pd += __shfl_xor(pd, msk, 64);
            }
            if (ok && (tx & 7) == 0) {
                int h0 = tx >> 3;  // OC=32, 8 lanes per head
                als[row * HEADS + h0] = ps;
                ald[row * HEADS + h0] = pd;
            }
        }
    }
}

// Fused: blocks [0,gblk) run layer-1 GEMM; the rest run the XCD-partitioned
// CSR scatter: group g = blockIdx&7 (aligned with round-robin block->XCD
// mapping) handles only dst in its 1/8 node range -> each csr/cursor line is
// written by ONE XCD (no cross-XCD writeback amplification).
__global__ __launch_bounds__(512) void gemm1_scatter(
    const float* __restrict__ A, const float* __restrict__ B,
    const float* __restrict__ asrc, const float* __restrict__ adst,
    __half* __restrict__ C, float* __restrict__ als, float* __restrict__ ald,
    int M, int gblk,
    const int* __restrict__ src, const int* __restrict__ dst,
    int* __restrict__ cursor, int* __restrict__ csr, int E, int N) {
    if ((int)blockIdx.x < gblk) {
        gemm_dev<128, 8, 4>(A, B, asrc, adst, C, als, ald, M, blockIdx.x);
        return;
    }
    int tid = threadIdx.y * 16 + threadIdx.x;
    int g = blockIdx.x & 7;                       // partition id (== XCD, heuristically)
    int c = (blockIdx.x - gblk) >> 3;             // chunk within partition
    int t = c * 512 + tid;
    int E4 = (E + 3) >> 2;
    int nspan = (N + 7) >> 3;
    int r0 = g * nspan;
    int r1 = r0 + nspan; if (r1 > N) r1 = N;
    if (t < E4) {
        int base = t * 4;
        if (base + 3 < E) {
            int4 s4 = *(const int4*)(src + base);
            int4 d4 = *(const int4*)(dst + base);
            if (d4.x >= r0 && d4.x < r1) { int p = atomicAdd(&cursor[d4.x], 1); csr[p] = s4.x; }
            if (d4.y >= r0 && d4.y < r1) { int p = atomicAdd(&cursor[d4.y], 1); csr[p] = s4.y; }
            if (d4.z >= r0 && d4.z < r1) { int p = atomicAdd(&cursor[d4.z], 1); csr[p] = s4.z; }
            if (d4.w >= r0 && d4.w < r1) { int p = atomicAdd(&cursor[d4.w], 1); csr[p] = s4.w; }
        } else {
            for (int k = 0; k < 4; ++k) {
                int e = base + k;
                if (e < E) {
                    int d = dst[e];
                    if (d >= r0 && d < r1) {
                        int p = atomicAdd(&cursor[d], 1);
                        csr[p] = src[e];
                    }
                }
            }
        }
    } else {
        int i = t - E4;
        if (i >= r0 && i < r1) {
            int p = atomicAdd(&cursor[i], 1);
            csr[p] = i;
        }
    }
}

// Layer-2 GEMM (standalone)
template <int BN, int TN, int HEADS>
__global__ __launch_bounds__(512) void gemm_fused(
    const float* __restrict__ A, const float* __restrict__ B,
    const float* __restrict__ asrc, const float* __restrict__ adst,
    __half* __restrict__ C, float* __restrict__ als, float* __restrict__ ald,
    int M) {
    gemm_dev<BN, TN, HEADS>(A, B, asrc, adst, C, als, ald, M, blockIdx.x);
}

// Node-parallel per-slot softmax numerators: 16 lanes walk one node's slots.
// dst == node (uniform), so only als[src] is gathered.
template <int HEADS>
__global__ void edge_ex_node(const float* __restrict__ als, const float* __restrict__ ald,
                             const int* __restrict__ csr, const int* __restrict__ off,
                             float* __restrict__ ex_t, int n, int ET) {
    int g = blockIdx.x * blockDim.x + threadIdx.x;
    int node = g >> 4;
    int lane = g & 15;
    if (node >= n) return;
    float ad[HEADS];
    if constexpr (HEADS == 4) {
        float4 a = ((const float4*)ald)[node];
        ad[0] = a.x; ad[1] = a.y; ad[2] = a.z; ad[3] = a.w;
    } else if constexpr (HEADS == 2) {
        float2 a = ((const float2*)ald)[node];
        ad[0] = a.x; ad[1] = a.y;
    } else {
        ad[0] = ald[node];
    }
    int e1 = off[node + 1];
    for (int e = off[node] + lane; e < e1; e += 16) {
        int s = csr[e];
        float av[HEADS];
        if constexpr (HEADS == 4) {
            float4 a = ((const float4*)als)[s];
            av[0] = a.x; av[1] = a.y; av[2] = a.z; av[3] = a.w;
        } else if constexpr (HEADS == 2) {
            float2 a = ((const float2*)als)[s];
            av[0] = a.x; av[1] = a.y;
        } else {
            av[0] = als[s];
        }
#pragma unroll
        for (int hd = 0; hd < HEADS; ++hd) {
            float lg = av[hd] + ad[hd];
            lg = lg > 0.f ? lg : 0.2f * lg;
            ex_t[(size_t)hd * ET + e] = __expf(lg);
        }
    }
}

// Layer-1 aggregation: one wave per dst node, 2 ch/lane (__half2 gather),
// 8-wide software pipeline, fp32 accumulate.
__global__ void gat_agg_l1(const __half* __restrict__ h, const float* __restrict__ ex_t,
                           const float* __restrict__ bias,
                           const int* __restrict__ off, const int* __restrict__ csr,
                           float* __restrict__ out, int n, int ET) {
    constexpr int P = 8;
    int wid = (blockIdx.x * blockDim.x + threadIdx.x) >> 6;
    int lane = threadIdx.x & 63;
    if (wid >= n) return;
    const int hd = lane >> 4;
    const __half2* h2 = (const __half2*)h + lane;
    const float* exp_ = ex_t + (size_t)hd * ET;
    int e0 = off[wid], e1 = off[wid + 1];
    float Sx = 0.f, Sy = 0.f, D = 0.f;

    float ex[P];
    __half2 hv[P];
#pragma unroll
    for (int p = 0; p < P; ++p) {
        int ee = e0 + p;
        int ie = (ee < e1) ? ee : e1 - 1;
        int s = csr[ie];
        float exv = exp_[ie];
        ex[p] = (ee < e1) ? exv : 0.f;
        hv[p] = h2[(size_t)s * 64];
    }
    int e = e0;
    for (; e + P < e1; e += P) {
        float nex[P];
        __half2 nhv[P];
#pragma unroll
        for (int p = 0; p < P; ++p) {
            int ee = e + P + p;
            int ie = (ee < e1) ? ee : e1 - 1;
            int s = csr[ie];
            float exv = exp_[ie];
            nex[p] = (ee < e1) ? exv : 0.f;
            nhv[p] = h2[(size_t)s * 64];
        }
#pragma unroll
        for (int p = 0; p < P; ++p) {
            D += ex[p];
            Sx = fmaf(ex[p], __low2float(hv[p]), Sx);
            Sy = fmaf(ex[p], __high2float(hv[p]), Sy);
            ex[p] = nex[p];
            hv[p] = nhv[p];
        }
    }
#pragma unroll
    for (int p = 0; p < P; ++p) {
        D += ex[p];
        Sx = fmaf(ex[p], __low2float(hv[p]), Sx);
        Sy = fmaf(ex[p], __high2float(hv[p]), Sy);
    }

    float inv = 1.f / D;
    float2 bv = ((const float2*)bias)[lane];
    float vx = Sx * inv + bv.x, vy = Sy * inv + bv.y;
    vx = vx > 0.f ? vx : (__expf(vx) - 1.f);
    vy = vy > 0.f ? vy : (__expf(vy) - 1.f);
    float2 o; o.x = vx; o.y = vy;
    ((float2*)out)[(size_t)wid * 64 + lane] = o;
}

// Layer-2 aggregation (C=64, fp16 h): 8-wide pipeline, 1 ch/lane, fused
// layer-3 feature head (h3 = elu(agg+b2) . W3, plus its logit terms).
__global__ void gat_agg_l2(const __half* __restrict__ h, const float* __restrict__ ex_t,
                           const float* __restrict__ bias,
                           const int* __restrict__ off, const int* __restrict__ csr,
                           const float* __restrict__ W3, const float* __restrict__ as3,
                           const float* __restrict__ ad3, float* __restrict__ h3,
                           float* __restrict__ als3, float* __restrict__ ald3,
                           int n, int ET) {
    constexpr int P = 8;
    int wid = (blockIdx.x * blockDim.x + threadIdx.x) >> 6;
    int lane = threadIdx.x & 63;
    if (wid >= n) return;
    const int hd = lane >> 5;
    const __half* hp = h + lane;
    const float* exp_ = ex_t + (size_t)hd * ET;
    int e0 = off[wid], e1 = off[wid + 1];
    float S = 0.f, D = 0.f;

    float ex[P];
    __half hv[P];
#pragma unroll
    for (int p = 0; p < P; ++p) {
        int ee = e0 + p;
        int ie = (ee < e1) ? ee : e1 - 1;
        int s = csr[ie];
        float exv = exp_[ie];
        ex[p] = (ee < e1) ? exv : 0.f;
        hv[p] = hp[(size_t)s * 64];
    }
    int e = e0;
    for (; e + P < e1; e += P) {
        float nex[P];
        __half nhv[P];
#pragma unroll
        for (int p = 0; p < P; ++p) {
            int ee = e + P + p;
            int ie = (ee < e1) ? ee : e1 - 1;
            int s = csr[ie];
            float exv = exp_[ie];
            nex[p] = (ee < e1) ? exv : 0.f;
            nhv[p] = hp[(size_t)s * 64];
        }
#pragma unroll
        for (int p = 0; p < P; ++p) {
            D += ex[p];
            S = fmaf(ex[p], __half2float(hv[p]), S);
            ex[p] = nex[p];
            hv[p] = nhv[p];
        }
    }
#pragma unroll
    for (int p = 0; p < P; ++p) {
        D += ex[p];
        S = fmaf(ex[p], __half2float(hv[p]), S);
    }

    float v = S / D + bias[lane];
    v = v > 0.f ? v : (__expf(v) - 1.f);     // a2[wid][lane]
    float r = v * W3[lane];
#pragma unroll
    for (int msk = 1; msk < 64; msk <<= 1) r += __shfl_xor(r, msk, 64);
    if (lane == 0) {
        h3[wid] = r;
        als3[wid] = r * as3[0];
        ald3[wid] = r * ad3[0];
    }
}

// Layer-3 aggregation: scalar channel, thread per node, 2-wide pipeline.
__global__ void gat_agg1(const float* __restrict__ h, const float* __restrict__ ex_t,
                         const float* __restrict__ bias,
                         const int* __restrict__ off, const int* __restrict__ csr,
                         float* __restrict__ out, int n) {
    int i = blockIdx.x * blockDim.x + threadIdx.x;
    if (i >= n) return;
    int e0 = off[i], e1 = off[i + 1];
    float S = 0.f, D = 0.f;
    float ex[2], hv[2];
#pragma unroll
    for (int p = 0; p < 2; ++p) {
        int ee = e0 + p;
        int ie = (ee < e1) ? ee : e1 - 1;
        int s = csr[ie];
        float exv = ex_t[ie];
        ex[p] = (ee < e1) ? exv : 0.f;
        hv[p] = h[s];
    }
    int e = e0;
    for (; e + 2 < e1; e += 2) {
#pragma unroll
        for (int p = 0; p < 2; ++p) {
            int ee = e + 2 + p;
            int ie = (ee < e1) ? ee : e1 - 1;
            int s = csr[ie];
            float exv = ex_t[ie];
            float nex = (ee < e1) ? exv : 0.f;
            float nhv = h[s];
            D += ex[p];
            S = fmaf(ex[p], hv[p], S);
            ex[p] = nex;
            hv[p] = nhv;
        }
    }
#pragma unroll
    for (int p = 0; p < 2; ++p) {
        D += ex[p];
        S = fmaf(ex[p], hv[p], S);
    }
    out[i] = S / D + bias[0];
}

extern "C" void kernel_launch(void* const* d_in, const int* in_sizes, int n_in,
                              void* d_out, int out_size, void* d_ws, size_t ws_size,
                              hipStream_t stream) {
    const float* x   = (const float*)d_in[0];
    const int*   ei  = (const int*)d_in[1];
    const float* W1  = (const float*)d_in[2];
    const float* as1 = (const float*)d_in[3];
    const float* ad1 = (const float*)d_in[4];
    const float* b1  = (const float*)d_in[5];
    const float* W2  = (const float*)d_in[6];
    const float* as2 = (const float*)d_in[7];
    const float* ad2 = (const float*)d_in[8];
    const float* b2  = (const float*)d_in[9];
    const float* W3  = (const float*)d_in[10];
    const float* as3 = (const float*)d_in[11];
    const float* ad3 = (const float*)d_in[12];
    const float* b3  = (const float*)d_in[13];
    float* out = (float*)d_out;

    const int N = in_sizes[0] / F_IN;  // 50000
    const int E = in_sizes[1] / 2;     // 800000
    const int ET = E + N;

    char* w = (char*)d_ws;
    size_t o = 0;
    auto alloc = [&](size_t bytes) -> void* {
        void* p = w + o;
        o += (bytes + 255) & ~(size_t)255;
        return p;
    };
    __half* hbuf = (__half*)alloc((size_t)N * 128 * 2);  // h1; reused as h2
    float* a1   = (float*)alloc((size_t)N * 128 * 4);
    float* h3   = (float*)alloc((size_t)N * 4);
    float* als  = (float*)alloc((size_t)N * 4 * 4);
    float* ald  = (float*)alloc((size_t)N * 4 * 4);
    float* als3 = (float*)alloc((size_t)N * 4);
    float* ald3 = (float*)alloc((size_t)N * 4);
    int* deg    = (int*)alloc((size_t)(N + 1) * 4);
    int* off    = (int*)alloc((size_t)(N + 1) * 4);
    int* cursor = (int*)alloc((size_t)N * 4);
    int* bsums  = (int*)alloc(1024);
    int* csr    = (int*)alloc((size_t)ET * 4);
    float* exb  = (float*)alloc((size_t)4 * ET * 4);   // reused per layer

    __half* h2 = hbuf;              // h1 dead after agg_l1

    const int* esrc = ei;
    const int* edst = ei + E;

    // ---- CSR offsets ----
    zero_int<<<(N + 1 + 255) / 256, 256, 0, stream>>>(deg, N + 1);
    count_deg4<<<((E + 3) / 4 + 255) / 256, 256, 0, stream>>>(edst, deg, E);
    int n1 = N + 1;
    int nb = (n1 + SB - 1) / SB;
    scan1<<<nb, SB, 0, stream>>>(deg, off, bsums, n1, N);   // +1 self-loop each
    scan2<<<1, SB, 0, stream>>>(bsums, nb);
    scan3<<<nb, SB, 0, stream>>>(off, cursor, bsums, n1, N);

    const int gblk = (N + 127) / 128;

    // ---- Layer-1 GEMM fused with XCD-partitioned CSR scatter ----
    {
        int E4 = (E + 3) >> 2;
        int spg = (E4 + N + 511) / 512;   // blocks per partition
        int sblk = 8 * spg;
        gemm1_scatter<<<gblk + sblk, dim3(16, 32), 0, stream>>>(
            x, W1, as1, ad1, hbuf, als, ald, N, gblk,
            esrc, edst, cursor, csr, E, N);
    }

    const int exblk = (N * 16 + 255) / 256;

    // ---- Layer 1 softmax + aggregation ----
    edge_ex_node<4><<<exblk, 256, 0, stream>>>(als, ald, csr, off, exb, N, ET);
    gat_agg_l1<<<(N * 64 + 255) / 256, 256, 0, stream>>>(
        hbuf, exb, b1, off, csr, a1, N, ET);

    // ---- Layer 2: 128 -> 2 heads x 32, concat, ELU (+ fused layer-3 head) ----
    gemm_fused<64, 4, 2><<<gblk, dim3(16, 32), 0, stream>>>(
        a1, W2, as2, ad2, h2, als, ald, N);
    edge_ex_node<2><<<exblk, 256, 0, stream>>>(als, ald, csr, off, exb, N, ET);
    gat_agg_l2<<<(N * 64 + 255) / 256, 256, 0, stream>>>(
        h2, exb, b2, off, csr, W3, as3, ad3, h3, als3, ald3, N, ET);

    // ---- Layer 3: aggregation of scalar feature ----
    edge_ex_node<1><<<exblk, 256, 0, stream>>>(als3, ald3, csr, off, exb, N, ET);
    gat_agg1<<<(N + 255) / 256, 256, 0, stream>>>(h3, exb, b3, off, csr, out, N);
}

// Round 11
// 205.502 us; speedup vs baseline: 1.4652x; 1.0679x over previous
//
#include <hip/hip_runtime.h>
#include <hip/hip_fp16.h>
#include <math.h>

#define F_IN 128
constexpr int SB = 256;

// 4 edges/thread, int4 loads, fire-and-forget atomics (self-loops folded into scan).
__global__ void count_deg4(const int* __restrict__ dst, int* __restrict__ deg, int E) {
    int t = blockIdx.x * 256 + threadIdx.x;
    int base = t * 4;
    if (base + 3 < E) {
        int4 d = *(const int4*)(dst + base);
        atomicAdd(&deg[d.x], 1);
        atomicAdd(&deg[d.y], 1);
        atomicAdd(&deg[d.z], 1);
        atomicAdd(&deg[d.w], 1);
    } else {
        for (int k = 0; k < 4; ++k) {
            int e = base + k;
            if (e < E) atomicAdd(&deg[dst[e]], 1);
        }
    }
}

// 3-kernel exclusive scan; +1 per element for i<selfN (self-loops)
__global__ void scan1(const int* __restrict__ in, int* __restrict__ out,
                      int* __restrict__ bsums, int n, int selfN) {
    __shared__ int sm[SB];
    int i = blockIdx.x * SB + threadIdx.x;
    int v = (i < n) ? (in[i] + (i < selfN ? 1 : 0)) : 0;
    sm[threadIdx.x] = v;
    __syncthreads();
    for (int d = 1; d < SB; d <<= 1) {
        int t = (threadIdx.x >= d) ? sm[threadIdx.x - d] : 0;
        __syncthreads();
        sm[threadIdx.x] += t;
        __syncthreads();
    }
    if (i < n) out[i] = sm[threadIdx.x] - v;
    if (threadIdx.x == SB - 1) bsums[blockIdx.x] = sm[SB - 1];
}

__global__ void scan2(int* __restrict__ bsums, int nb) {
    __shared__ int sm[SB];
    int v = (threadIdx.x < nb) ? bsums[threadIdx.x] : 0;
    sm[threadIdx.x] = v;
    __syncthreads();
    for (int d = 1; d < SB; d <<= 1) {
        int t = (threadIdx.x >= d) ? sm[threadIdx.x - d] : 0;
        __syncthreads();
        sm[threadIdx.x] += t;
        __syncthreads();
    }
    if (threadIdx.x < nb) bsums[threadIdx.x] = sm[threadIdx.x] - v;
}

__global__ void scan3(int* __restrict__ off, int* __restrict__ cursor,
                      const int* __restrict__ bsums, int n, int ncur) {
    int i = blockIdx.x * SB + threadIdx.x;
    if (i < n) {
        int v = off[i] + bsums[blockIdx.x];
        off[i] = v;
        if (i < ncur) cursor[i] = v;
    }
}

// GEMM body; A may be float or __half. Bank-conflict-free column chunks
// {tx*4, 64+tx*4}. fp16 C output + fp32 attention-logit epilogue.
template <int BN, int TN, int HEADS, typename AT>
__device__ __forceinline__ void gemm_dev(
    const AT* __restrict__ A, const float* __restrict__ B,
    const float* __restrict__ asrc, const float* __restrict__ adst,
    __half* __restrict__ C, float* __restrict__ als, float* __restrict__ ald,
    int M, int bid) {
    constexpr int BM = 128, BK = 16, TM = 4, K = 128;
    __shared__ float As[BK][BM + 4];
    __shared__ float Bs[BK][BN];
    const int tx = threadIdx.x, ty = threadIdx.y;
    const int tid = ty * 16 + tx;
    const int row0 = bid * BM;
    const int i0 = ty * TM;
    const int j0a = tx * 4;
    const int j0b = 64 + tx * 4;

    float acc[TM][TN];
#pragma unroll
    for (int m = 0; m < TM; ++m)
#pragma unroll
        for (int n = 0; n < TN; ++n) acc[m][n] = 0.f;

    const int ar = tid >> 2;
    const int ak = (tid & 3) * 4;
    int arow = row0 + ar;
    if (arow >= M) arow = M - 1;
    const AT* Aptr = A + (size_t)arow * K + ak;
    const int bk = (BN == 128) ? (tid >> 5) : (tid >> 4);
    const int bc = (BN == 128) ? ((tid & 31) * 4) : ((tid & 15) * 4);
    const bool bact = (BN == 128) || (tid < 256);

    for (int kc = 0; kc < K; kc += BK) {
        float a0, a1v, a2v, a3v;
        if constexpr (sizeof(AT) == 4) {
            float4 av = *(const float4*)(Aptr + kc);
            a0 = av.x; a1v = av.y; a2v = av.z; a3v = av.w;
        } else {
            uint2 raw = *(const uint2*)(Aptr + kc);
            __half2 h01 = *(__half2*)&raw.x;
            __half2 h23 = *(__half2*)&raw.y;
            float2 f01 = __half22float2(h01);
            float2 f23 = __half22float2(h23);
            a0 = f01.x; a1v = f01.y; a2v = f23.x; a3v = f23.y;
        }
        float4 bv;
        if (bact) bv = *(const float4*)(B + (size_t)(kc + bk) * BN + bc);
        __syncthreads();
        As[ak + 0][ar] = a0;
        As[ak + 1][ar] = a1v;
        As[ak + 2][ar] = a2v;
        As[ak + 3][ar] = a3v;
        if (bact) *(float4*)&Bs[bk][bc] = bv;
        __syncthreads();
#pragma unroll
        for (int kk = 0; kk < BK; ++kk) {
            float4 a4 = *(const float4*)&As[kk][i0];
            float arr[TM] = {a4.x, a4.y, a4.z, a4.w};
            float br[TN];
            float4 b0 = *(const float4*)&Bs[kk][j0a];
            br[0] = b0.x; br[1] = b0.y; br[2] = b0.z; br[3] = b0.w;
            if constexpr (TN == 8) {
                float4 b1 = *(const float4*)&Bs[kk][j0b];
                br[4] = b1.x; br[5] = b1.y; br[6] = b1.z; br[7] = b1.w;
            }
#pragma unroll
            for (int m = 0; m < TM; ++m)
#pragma unroll
                for (int n = 0; n < TN; ++n) acc[m][n] += arr[m] * br[n];
        }
    }

#pragma unroll
    for (int m = 0; m < TM; ++m) {
        int row = row0 + i0 + m;
        bool ok = row < M;
        if constexpr (TN == 8) {
            if (ok) {
                alignas(8) __half2 pa[2], pb[2];
#pragma unroll
                for (int n2 = 0; n2 < 2; ++n2) {
                    pa[n2] = __floats2half2_rn(acc[m][2 * n2], acc[m][2 * n2 + 1]);
                    pb[n2] = __floats2half2_rn(acc[m][4 + 2 * n2], acc[m][5 + 2 * n2]);
                }
                *(uint2*)&C[(size_t)row * BN + j0a] = *(uint2*)pa;
                *(uint2*)&C[(size_t)row * BN + j0b] = *(uint2*)pb;
            }
            float psA = 0.f, pdA = 0.f, psB = 0.f, pdB = 0.f;
#pragma unroll
            for (int n = 0; n < 4; ++n) {
                psA += acc[m][n] * asrc[j0a + n];
                pdA += acc[m][n] * adst[j0a + n];
                psB += acc[m][n + 4] * asrc[j0b + n];
                pdB += acc[m][n + 4] * adst[j0b + n];
            }
#pragma unroll
            for (int msk = 1; msk < 8; msk <<= 1) {
                psA += __shfl_xor(psA, msk, 64);
                pdA += __shfl_xor(pdA, msk, 64);
                psB += __shfl_xor(psB, msk, 64);
                pdB += __shfl_xor(pdB, msk, 64);
            }
            if (ok && (tx & 7) == 0) {
                int hA = tx >> 3;
                als[row * HEADS + hA] = psA;
                ald[row * HEADS + hA] = pdA;
                als[row * HEADS + 2 + hA] = psB;
                ald[row * HEADS + 2 + hA] = pdB;
            }
        } else {
            if (ok) {
                alignas(8) __half2 ph[2];
#pragma unroll
                for (int n2 = 0; n2 < 2; ++n2)
                    ph[n2] = __floats2half2_rn(acc[m][2 * n2], acc[m][2 * n2 + 1]);
                *(uint2*)&C[(size_t)row * BN + j0a] = *(uint2*)ph;
            }
            float ps = 0.f, pd = 0.f;
#pragma unroll
            for (int n = 0; n < TN; ++n) {
                ps += acc[m][n] * asrc[j0a + n];
                pd += acc[m][n] * adst[j0a + n];
            }
#pragma unroll
            for (int msk = 1; msk < 8; msk <<= 1) {
                ps += __shfl_xor(ps, msk, 64);
                pd += __shfl_xor(pd, msk, 64);
            }
            if (ok && (tx & 7) == 0) {
                int h0 = tx >> 3;
                als[row * HEADS + h0] = ps;
                ald[row * HEADS + h0] = pd;
            }
        }
    }
}

// Fused: blocks [0,gblk) run layer-1 GEMM; the rest run the XCD-partitioned
// CSR scatter (partition g = blockIdx&7 handles dst in its 1/8 node range).
__global__ __launch_bounds__(512) void gemm1_scatter(
    const float* __restrict__ A, const float* __restrict__ B,
    const float* __restrict__ asrc, const float* __restrict__ adst,
    __half* __restrict__ C, float* __restrict__ als, float* __restrict__ ald,
    int M, int gblk,
    const int* __restrict__ src, const int* __restrict__ dst,
    int* __restrict__ cursor, int* __restrict__ csr, int E, int N) {
    if ((int)blockIdx.x < gblk) {
        gemm_dev<128, 8, 4, float>(A, B, asrc, adst, C, als, ald, M, blockIdx.x);
        return;
    }
    int tid = threadIdx.y * 16 + threadIdx.x;
    int g = blockIdx.x & 7;
    int c = (blockIdx.x - gblk) >> 3;
    int t = c * 512 + tid;
    int E4 = (E + 3) >> 2;
    int nspan = (N + 7) >> 3;
    int r0 = g * nspan;
    int r1 = r0 + nspan; if (r1 > N) r1 = N;
    if (t < E4) {
        int base = t * 4;
        if (base + 3 < E) {
            int4 s4 = *(const int4*)(src + base);
            int4 d4 = *(const int4*)(dst + base);
            if (d4.x >= r0 && d4.x < r1) { int p = atomicAdd(&cursor[d4.x], 1); csr[p] = s4.x; }
            if (d4.y >= r0 && d4.y < r1) { int p = atomicAdd(&cursor[d4.y], 1); csr[p] = s4.y; }
            if (d4.z >= r0 && d4.z < r1) { int p = atomicAdd(&cursor[d4.z], 1); csr[p] = s4.z; }
            if (d4.w >= r0 && d4.w < r1) { int p = atomicAdd(&cursor[d4.w], 1); csr[p] = s4.w; }
        } else {
            for (int k = 0; k < 4; ++k) {
                int e = base + k;
                if (e < E) {
                    int d = dst[e];
                    if (d >= r0 && d < r1) {
                        int p = atomicAdd(&cursor[d], 1);
                        csr[p] = src[e];
                    }
                }
            }
        }
    } else {
        int i = t - E4;
        if (i >= r0 && i < r1) {
            int p = atomicAdd(&cursor[i], 1);
            csr[p] = i;
        }
    }
}

// Layer-2 GEMM (standalone, fp16 A)
template <int BN, int TN, int HEADS>
__global__ __launch_bounds__(512) void gemm_fused_h(
    const __half* __restrict__ A, const float* __restrict__ B,
    const float* __restrict__ asrc, const float* __restrict__ adst,
    __half* __restrict__ C, float* __restrict__ als, float* __restrict__ ald,
    int M) {
    gemm_dev<BN, TN, HEADS, __half>(A, B, asrc, adst, C, als, ald, M, blockIdx.x);
}

// Layer-1 aggregation: one wave per dst node, 2 ch/lane (__half2 gather),
// 8-wide pipeline, INLINE softmax numerator: lanes of the same head broadcast-
// load als[s*4+hd] (L2-resident), ald is node-uniform. fp16 output (a1).
__global__ void gat_agg_l1(const __half* __restrict__ h,
                           const float* __restrict__ als, const float* __restrict__ ald,
                           const float* __restrict__ bias,
                           const int* __restrict__ off, const int* __restrict__ csr,
                           __half* __restrict__ out, int n) {
    constexpr int P = 8;
    int wid = (blockIdx.x * blockDim.x + threadIdx.x) >> 6;
    int lane = threadIdx.x & 63;
    if (wid >= n) return;
    const int hd = lane >> 4;
    const __half2* h2 = (const __half2*)h + lane;
    float ad = ald[wid * 4 + hd];
    int e0 = off[wid], e1 = off[wid + 1];
    float Sx = 0.f, Sy = 0.f, D = 0.f;

    float al[P];
    __half2 hv[P];
#pragma unroll
    for (int p = 0; p < P; ++p) {
        int ee = e0 + p;
        int ie = (ee < e1) ? ee : e1 - 1;
        int s = csr[ie];
        float av = als[s * 4 + hd];
        al[p] = (ee < e1) ? av : -1e30f;   // exp -> 0 for pad slots
        hv[p] = h2[(size_t)s * 64];
    }
    int e = e0;
    for (; e + P < e1; e += P) {
        float nal[P];
        __half2 nhv[P];
#pragma unroll
        for (int p = 0; p < P; ++p) {
            int ee = e + P + p;
            int ie = (ee < e1) ? ee : e1 - 1;
            int s = csr[ie];
            float av = als[s * 4 + hd];
            nal[p] = (ee < e1) ? av : -1e30f;
            nhv[p] = h2[(size_t)s * 64];
        }
#pragma unroll
        for (int p = 0; p < P; ++p) {
            float lg = al[p] + ad;
            lg = lg > 0.f ? lg : 0.2f * lg;
            float exv = __expf(lg);
            D += exv;
            Sx = fmaf(exv, __low2float(hv[p]), Sx);
            Sy = fmaf(exv, __high2float(hv[p]), Sy);
            al[p] = nal[p];
            hv[p] = nhv[p];
        }
    }
#pragma unroll
    for (int p = 0; p < P; ++p) {
        float lg = al[p] + ad;
        lg = lg > 0.f ? lg : 0.2f * lg;
        float exv = __expf(lg);
        D += exv;
        Sx = fmaf(exv, __low2float(hv[p]), Sx);
        Sy = fmaf(exv, __high2float(hv[p]), Sy);
    }

    float inv = 1.f / D;
    float2 bv = ((const float2*)bias)[lane];
    float vx = Sx * inv + bv.x, vy = Sy * inv + bv.y;
    vx = vx > 0.f ? vx : (__expf(vx) - 1.f);
    vy = vy > 0.f ? vy : (__expf(vy) - 1.f);
    ((__half2*)out)[(size_t)wid * 64 + lane] = __floats2half2_rn(vx, vy);
}

// Layer-2 aggregation (C=64, fp16 h): 8-wide pipeline, 1 ch/lane, inline exp,
// fused layer-3 head. Writes packed {h3, als3} (one 8B gather for layer 3).
__global__ void gat_agg_l2(const __half* __restrict__ h,
                           const float* __restrict__ als, const float* __restrict__ ald,
                           const float* __restrict__ bias,
                           const int* __restrict__ off, const int* __restrict__ csr,
                           const float* __restrict__ W3, const float* __restrict__ as3,
                           const float* __restrict__ ad3, float2* __restrict__ hs,
                           float* __restrict__ ald3, int n) {
    constexpr int P = 8;
    int wid = (blockIdx.x * blockDim.x + threadIdx.x) >> 6;
    int lane = threadIdx.x & 63;
    if (wid >= n) return;
    const int hd = lane >> 5;
    const __half* hp = h + lane;
    float ad = ald[wid * 2 + hd];
    int e0 = off[wid], e1 = off[wid + 1];
    float S = 0.f, D = 0.f;

    float al[P];
    __half hv[P];
#pragma unroll
    for (int p = 0; p < P; ++p) {
        int ee = e0 + p;
        int ie = (ee < e1) ? ee : e1 - 1;
        int s = csr[ie];
        float av = als[s * 2 + hd];
        al[p] = (ee < e1) ? av : -1e30f;
        hv[p] = hp[(size_t)s * 64];
    }
    int e = e0;
    for (; e + P < e1; e += P) {
        float nal[P];
        __half nhv[P];
#pragma unroll
        for (int p = 0; p < P; ++p) {
            int ee = e + P + p;
            int ie = (ee < e1) ? ee : e1 - 1;
            int s = csr[ie];
            float av = als[s * 2 + hd];
            nal[p] = (ee < e1) ? av : -1e30f;
            nhv[p] = hp[(size_t)s * 64];
        }
#pragma unroll
        for (int p = 0; p < P; ++p) {
            float lg = al[p] + ad;
            lg = lg > 0.f ? lg : 0.2f * lg;
            float exv = __expf(lg);
            D += exv;
            S = fmaf(exv, __half2float(hv[p]), S);
            al[p] = nal[p];
            hv[p] = nhv[p];
        }
    }
#pragma unroll
    for (int p = 0; p < P; ++p) {
        float lg = al[p] + ad;
        lg = lg > 0.f ? lg : 0.2f * lg;
        float exv = __expf(lg);
        D += exv;
        S = fmaf(exv, __half2float(hv[p]), S);
    }

    float v = S / D + bias[lane];
    v = v > 0.f ? v : (__expf(v) - 1.f);     // a2[wid][lane]
    float r = v * W3[lane];
#pragma unroll
    for (int msk = 1; msk < 64; msk <<= 1) r += __shfl_xor(r, msk, 64);
    if (lane == 0) {
        hs[wid] = make_float2(r, r * as3[0]);  // {h3, als3}
        ald3[wid] = r * ad3[0];
    }
}

// Layer-3 aggregation: thread per node, 2-wide pipeline, single packed gather.
__global__ void gat_agg1(const float2* __restrict__ hs, const float* __restrict__ ald3,
                         const float* __restrict__ bias,
                         const int* __restrict__ off, const int* __restrict__ csr,
                         float* __restrict__ out, int n) {
    int i = blockIdx.x * blockDim.x + threadIdx.x;
    if (i >= n) return;
    float ad = ald3[i];
    int e0 = off[i], e1 = off[i + 1];
    float S = 0.f, D = 0.f;
    float2 g[2];
    float valid[2];
#pragma unroll
    for (int p = 0; p < 2; ++p) {
        int ee = e0 + p;
        int ie = (ee < e1) ? ee : e1 - 1;
        int s = csr[ie];
        g[p] = hs[s];
        valid[p] = (ee < e1) ? 0.f : -1e30f;
    }
    int e = e0;
    for (; e + 2 < e1; e += 2) {
#pragma unroll
        for (int p = 0; p < 2; ++p) {
            int ee = e + 2 + p;
            int ie = (ee < e1) ? ee : e1 - 1;
            int s = csr[ie];
            float2 ng = hs[s];
            float nvalid = (ee < e1) ? 0.f : -1e30f;
            float lg = g[p].y + ad + valid[p];
            lg = lg > 0.f ? lg : 0.2f * lg;
            float exv = __expf(lg);
            D += exv;
            S = fmaf(exv, g[p].x, S);
            g[p] = ng;
            valid[p] = nvalid;
        }
    }
#pragma unroll
    for (int p = 0; p < 2; ++p) {
        float lg = g[p].y + ad + valid[p];
        lg = lg > 0.f ? lg : 0.2f * lg;
        float exv = __expf(lg);
        D += exv;
        S = fmaf(exv, g[p].x, S);
    }
    out[i] = S / D + bias[0];
}

extern "C" void kernel_launch(void* const* d_in, const int* in_sizes, int n_in,
                              void* d_out, int out_size, void* d_ws, size_t ws_size,
                              hipStream_t stream) {
    const float* x   = (const float*)d_in[0];
    const int*   ei  = (const int*)d_in[1];
    const float* W1  = (const float*)d_in[2];
    const float* as1 = (const float*)d_in[3];
    const float* ad1 = (const float*)d_in[4];
    const float* b1  = (const float*)d_in[5];
    const float* W2  = (const float*)d_in[6];
    const float* as2 = (const float*)d_in[7];
    const float* ad2 = (const float*)d_in[8];
    const float* b2  = (const float*)d_in[9];
    const float* W3  = (const float*)d_in[10];
    const float* as3 = (const float*)d_in[11];
    const float* ad3 = (const float*)d_in[12];
    const float* b3  = (const float*)d_in[13];
    float* out = (float*)d_out;

    const int N = in_sizes[0] / F_IN;  // 50000
    const int E = in_sizes[1] / 2;     // 800000
    const int ET = E + N;

    char* w = (char*)d_ws;
    size_t o = 0;
    auto alloc = [&](size_t bytes) -> void* {
        void* p = w + o;
        o += (bytes + 255) & ~(size_t)255;
        return p;
    };
    __half* hbuf = (__half*)alloc((size_t)N * 128 * 2);  // h1; reused as h2
    __half* a1   = (__half*)alloc((size_t)N * 128 * 2);
    float2* hs   = (float2*)alloc((size_t)N * 8);        // {h3, als3}
    float* als  = (float*)alloc((size_t)N * 4 * 4);
    float* ald  = (float*)alloc((size_t)N * 4 * 4);
    float* ald3 = (float*)alloc((size_t)N * 4);
    int* deg    = (int*)alloc((size_t)(N + 1) * 4);
    int* off    = (int*)alloc((size_t)(N + 1) * 4);
    int* cursor = (int*)alloc((size_t)N * 4);
    int* bsums  = (int*)alloc(1024);
    int* csr    = (int*)alloc((size_t)ET * 4);

    __half* h2 = hbuf;              // h1 dead after agg_l1

    const int* esrc = ei;
    const int* edst = ei + E;

    // ---- CSR offsets ----
    hipMemsetAsync(deg, 0, (size_t)(N + 1) * 4, stream);
    count_deg4<<<((E + 3) / 4 + 255) / 256, 256, 0, stream>>>(edst, deg, E);
    int n1 = N + 1;
    int nb = (n1 + SB - 1) / SB;
    scan1<<<nb, SB, 0, stream>>>(deg, off, bsums, n1, N);   // +1 self-loop each
    scan2<<<1, SB, 0, stream>>>(bsums, nb);
    scan3<<<nb, SB, 0, stream>>>(off, cursor, bsums, n1, N);

    const int gblk = (N + 127) / 128;

    // ---- Layer-1 GEMM fused with XCD-partitioned CSR scatter ----
    {
        int E4 = (E + 3) >> 2;
        int spg = (E4 + N + 511) / 512;   // blocks per partition
        int sblk = 8 * spg;
        gemm1_scatter<<<gblk + sblk, dim3(16, 32), 0, stream>>>(
            x, W1, as1, ad1, hbuf, als, ald, N, gblk,
            esrc, edst, cursor, csr, E, N);
    }

    // ---- Layer 1 aggregation (inline softmax) ----
    gat_agg_l1<<<(N * 64 + 255) / 256, 256, 0, stream>>>(
        hbuf, als, ald, b1, off, csr, a1, N);

    // ---- Layer 2: GEMM (fp16 A) + aggregation (inline softmax, fused l3 head) ----
    gemm_fused_h<64, 4, 2><<<gblk, dim3(16, 32), 0, stream>>>(
        a1, W2, as2, ad2, h2, als, ald, N);
    gat_agg_l2<<<(N * 64 + 255) / 256, 256, 0, stream>>>(
        h2, als, ald, b2, off, csr, W3, as3, ad3, hs, ald3, N);

    // ---- Layer 3: aggregation of packed scalar feature ----
    gat_agg1<<<(N + 255) / 256, 256, 0, stream>>>(hs, ald3, b3, off, csr, out, N);
}

// Round 12
// 182.179 us; speedup vs baseline: 1.6528x; 1.1280x over previous
//
#include <hip/hip_runtime.h>
#include <hip/hip_fp16.h>
#include <math.h>

#define F_IN 128
constexpr int SB = 256;
constexpr float LOG2E = 1.4426950408889634f;

// 4 edges/thread, int4 loads, fire-and-forget atomics (self-loops folded into scan).
__global__ void count_deg4(const int* __restrict__ dst, int* __restrict__ deg, int E) {
    int t = blockIdx.x * 256 + threadIdx.x;
    int base = t * 4;
    if (base + 3 < E) {
        int4 d = *(const int4*)(dst + base);
        atomicAdd(&deg[d.x], 1);
        atomicAdd(&deg[d.y], 1);
        atomicAdd(&deg[d.z], 1);
        atomicAdd(&deg[d.w], 1);
    } else {
        for (int k = 0; k < 4; ++k) {
            int e = base + k;
            if (e < E) atomicAdd(&deg[dst[e]], 1);
        }
    }
}

// 3-kernel exclusive scan; +1 per element for i<selfN (self-loops)
__global__ void scan1(const int* __restrict__ in, int* __restrict__ out,
                      int* __restrict__ bsums, int n, int selfN) {
    __shared__ int sm[SB];
    int i = blockIdx.x * SB + threadIdx.x;
    int v = (i < n) ? (in[i] + (i < selfN ? 1 : 0)) : 0;
    sm[threadIdx.x] = v;
    __syncthreads();
    for (int d = 1; d < SB; d <<= 1) {
        int t = (threadIdx.x >= d) ? sm[threadIdx.x - d] : 0;
        __syncthreads();
        sm[threadIdx.x] += t;
        __syncthreads();
    }
    if (i < n) out[i] = sm[threadIdx.x] - v;
    if (threadIdx.x == SB - 1) bsums[blockIdx.x] = sm[SB - 1];
}

__global__ void scan2(int* __restrict__ bsums, int nb) {
    __shared__ int sm[SB];
    int v = (threadIdx.x < nb) ? bsums[threadIdx.x] : 0;
    sm[threadIdx.x] = v;
    __syncthreads();
    for (int d = 1; d < SB; d <<= 1) {
        int t = (threadIdx.x >= d) ? sm[threadIdx.x - d] : 0;
        __syncthreads();
        sm[threadIdx.x] += t;
        __syncthreads();
    }
    if (threadIdx.x < nb) bsums[threadIdx.x] = sm[threadIdx.x] - v;
}

__global__ void scan3(int* __restrict__ off, int* __restrict__ cursor,
                      const int* __restrict__ bsums, int n, int ncur) {
    int i = blockIdx.x * SB + threadIdx.x;
    if (i < n) {
        int v = off[i] + bsums[blockIdx.x];
        off[i] = v;
        if (i < ncur) cursor[i] = v;
    }
}

// GEMM body; A float or __half. Bank-conflict-free column chunks {tx*4,64+tx*4}.
// fp16 C output + fp32 attention-logit epilogue, logits PRE-SCALED by log2e.
template <int BN, int TN, int HEADS, typename AT>
__device__ __forceinline__ void gemm_dev(
    const AT* __restrict__ A, const float* __restrict__ B,
    const float* __restrict__ asrc, const float* __restrict__ adst,
    __half* __restrict__ C, float* __restrict__ als, float* __restrict__ ald,
    int M, int bid) {
    constexpr int BM = 128, BK = 16, TM = 4, K = 128;
    __shared__ float As[BK][BM + 4];
    __shared__ float Bs[BK][BN];
    const int tx = threadIdx.x, ty = threadIdx.y;
    const int tid = ty * 16 + tx;
    const int row0 = bid * BM;
    const int i0 = ty * TM;
    const int j0a = tx * 4;
    const int j0b = 64 + tx * 4;

    float acc[TM][TN];
#pragma unroll
    for (int m = 0; m < TM; ++m)
#pragma unroll
        for (int n = 0; n < TN; ++n) acc[m][n] = 0.f;

    const int ar = tid >> 2;
    const int ak = (tid & 3) * 4;
    int arow = row0 + ar;
    if (arow >= M) arow = M - 1;
    const AT* Aptr = A + (size_t)arow * K + ak;
    const int bk = (BN == 128) ? (tid >> 5) : (tid >> 4);
    const int bc = (BN == 128) ? ((tid & 31) * 4) : ((tid & 15) * 4);
    const bool bact = (BN == 128) || (tid < 256);

    for (int kc = 0; kc < K; kc += BK) {
        float a0, a1v, a2v, a3v;
        if constexpr (sizeof(AT) == 4) {
            float4 av = *(const float4*)(Aptr + kc);
            a0 = av.x; a1v = av.y; a2v = av.z; a3v = av.w;
        } else {
            uint2 raw = *(const uint2*)(Aptr + kc);
            __half2 h01 = *(__half2*)&raw.x;
            __half2 h23 = *(__half2*)&raw.y;
            float2 f01 = __half22float2(h01);
            float2 f23 = __half22float2(h23);
            a0 = f01.x; a1v = f01.y; a2v = f23.x; a3v = f23.y;
        }
        float4 bv;
        if (bact) bv = *(const float4*)(B + (size_t)(kc + bk) * BN + bc);
        __syncthreads();
        As[ak + 0][ar] = a0;
        As[ak + 1][ar] = a1v;
        As[ak + 2][ar] = a2v;
        As[ak + 3][ar] = a3v;
        if (bact) *(float4*)&Bs[bk][bc] = bv;
        __syncthreads();
#pragma unroll
        for (int kk = 0; kk < BK; ++kk) {
            float4 a4 = *(const float4*)&As[kk][i0];
            float arr[TM] = {a4.x, a4.y, a4.z, a4.w};
            float br[TN];
            float4 b0 = *(const float4*)&Bs[kk][j0a];
            br[0] = b0.x; br[1] = b0.y; br[2] = b0.z; br[3] = b0.w;
            if constexpr (TN == 8) {
                float4 b1 = *(const float4*)&Bs[kk][j0b];
                br[4] = b1.x; br[5] = b1.y; br[6] = b1.z; br[7] = b1.w;
            }
#pragma unroll
            for (int m = 0; m < TM; ++m)
#pragma unroll
                for (int n = 0; n < TN; ++n) acc[m][n] += arr[m] * br[n];
        }
    }

#pragma unroll
    for (int m = 0; m < TM; ++m) {
        int row = row0 + i0 + m;
        bool ok = row < M;
        if constexpr (TN == 8) {
            if (ok) {
                alignas(8) __half2 pa[2], pb[2];
#pragma unroll
                for (int n2 = 0; n2 < 2; ++n2) {
                    pa[n2] = __floats2half2_rn(acc[m][2 * n2], acc[m][2 * n2 + 1]);
                    pb[n2] = __floats2half2_rn(acc[m][4 + 2 * n2], acc[m][5 + 2 * n2]);
                }
                *(uint2*)&C[(size_t)row * BN + j0a] = *(uint2*)pa;
                *(uint2*)&C[(size_t)row * BN + j0b] = *(uint2*)pb;
            }
            float psA = 0.f, pdA = 0.f, psB = 0.f, pdB = 0.f;
#pragma unroll
            for (int n = 0; n < 4; ++n) {
                psA += acc[m][n] * asrc[j0a + n];
                pdA += acc[m][n] * adst[j0a + n];
                psB += acc[m][n + 4] * asrc[j0b + n];
                pdB += acc[m][n + 4] * adst[j0b + n];
            }
#pragma unroll
            for (int msk = 1; msk < 8; msk <<= 1) {
                psA += __shfl_xor(psA, msk, 64);
                pdA += __shfl_xor(pdA, msk, 64);
                psB += __shfl_xor(psB, msk, 64);
                pdB += __shfl_xor(pdB, msk, 64);
            }
            if (ok && (tx & 7) == 0) {
                int hA = tx >> 3;
                als[row * HEADS + hA] = psA * LOG2E;
                ald[row * HEADS + hA] = pdA * LOG2E;
                als[row * HEADS + 2 + hA] = psB * LOG2E;
                ald[row * HEADS + 2 + hA] = pdB * LOG2E;
            }
        } else {
            if (ok) {
                alignas(8) __half2 ph[2];
#pragma unroll
                for (int n2 = 0; n2 < 2; ++n2)
                    ph[n2] = __floats2half2_rn(acc[m][2 * n2], acc[m][2 * n2 + 1]);
                *(uint2*)&C[(size_t)row * BN + j0a] = *(uint2*)ph;
            }
            float ps = 0.f, pd = 0.f;
#pragma unroll
            for (int n = 0; n < TN; ++n) {
                ps += acc[m][n] * asrc[j0a + n];
                pd += acc[m][n] * adst[j0a + n];
            }
#pragma unroll
            for (int msk = 1; msk < 8; msk <<= 1) {
                ps += __shfl_xor(ps, msk, 64);
                pd += __shfl_xor(pd, msk, 64);
            }
            if (ok && (tx & 7) == 0) {
                int h0 = tx >> 3;
                als[row * HEADS + h0] = ps * LOG2E;
                ald[row * HEADS + h0] = pd * LOG2E;
            }
        }
    }
}

// Fused: blocks [0,gblk) run layer-1 GEMM; the rest run the XCD-partitioned
// CSR scatter (partition g = blockIdx&7 handles dst in its 1/8 node range).
__global__ __launch_bounds__(512) void gemm1_scatter(
    const float* __restrict__ A, const float* __restrict__ B,
    const float* __restrict__ asrc, const float* __restrict__ adst,
    __half* __restrict__ C, float* __restrict__ als, float* __restrict__ ald,
    int M, int gblk,
    const int* __restrict__ src, const int* __restrict__ dst,
    int* __restrict__ cursor, int* __restrict__ csr, int E, int N) {
    if ((int)blockIdx.x < gblk) {
        gemm_dev<128, 8, 4, float>(A, B, asrc, adst, C, als, ald, M, blockIdx.x);
        return;
    }
    int tid = threadIdx.y * 16 + threadIdx.x;
    int g = blockIdx.x & 7;
    int c = (blockIdx.x - gblk) >> 3;
    int t = c * 512 + tid;
    int E4 = (E + 3) >> 2;
    int nspan = (N + 7) >> 3;
    int r0 = g * nspan;
    int r1 = r0 + nspan; if (r1 > N) r1 = N;
    if (t < E4) {
        int base = t * 4;
        if (base + 3 < E) {
            int4 s4 = *(const int4*)(src + base);
            int4 d4 = *(const int4*)(dst + base);
            if (d4.x >= r0 && d4.x < r1) { int p = atomicAdd(&cursor[d4.x], 1); csr[p] = s4.x; }
            if (d4.y >= r0 && d4.y < r1) { int p = atomicAdd(&cursor[d4.y], 1); csr[p] = s4.y; }
            if (d4.z >= r0 && d4.z < r1) { int p = atomicAdd(&cursor[d4.z], 1); csr[p] = s4.z; }
            if (d4.w >= r0 && d4.w < r1) { int p = atomicAdd(&cursor[d4.w], 1); csr[p] = s4.w; }
        } else {
            for (int k = 0; k < 4; ++k) {
                int e = base + k;
                if (e < E) {
                    int d = dst[e];
                    if (d >= r0 && d < r1) {
                        int p = atomicAdd(&cursor[d], 1);
                        csr[p] = src[e];
                    }
                }
            }
        }
    } else {
        int i = t - E4;
        if (i >= r0 && i < r1) {
            int p = atomicAdd(&cursor[i], 1);
            csr[p] = i;
        }
    }
}

// Layer-2 GEMM (standalone, fp16 A)
template <int BN, int TN, int HEADS>
__global__ __launch_bounds__(512) void gemm_fused_h(
    const __half* __restrict__ A, const float* __restrict__ B,
    const float* __restrict__ asrc, const float* __restrict__ adst,
    __half* __restrict__ C, float* __restrict__ als, float* __restrict__ ald,
    int M) {
    gemm_dev<BN, TN, HEADS, __half>(A, B, asrc, adst, C, als, ald, M, blockIdx.x);
}

// Layer-1 aggregation, edge-group layout: wave = 1 node; 4 groups x 16 lanes;
// group g processes edge (e + g), lane holds 8 channels (uint4 fp16 gather).
// Per-edge scalar VALU (logit add/leaky/exp2/D) amortized 4x. 2-stage pipeline
// (8 edges in flight). Cross-group shfl reduce at end. fp16 out.
__global__ void gat_agg_l1(const __half* __restrict__ h,
                           const float* __restrict__ als, const float* __restrict__ ald,
                           const float* __restrict__ bias,
                           const int* __restrict__ off, const int* __restrict__ csr,
                           __half* __restrict__ out, int n) {
    int wid = (blockIdx.x * blockDim.x + threadIdx.x) >> 6;
    int lane = threadIdx.x & 63;
    if (wid >= n) return;
    const int g = lane >> 4;    // edge sub-slot 0..3
    const int q = lane & 15;    // channel-quarter: 8 channels at q*8
    const int hd = q >> 2;      // head of those channels
    float ad = ald[wid * 4 + hd];   // pre-scaled by log2e
    int e0 = off[wid], e1 = off[wid + 1];
    const __half* hq = h + q * 8;

    float acc[8] = {0.f, 0.f, 0.f, 0.f, 0.f, 0.f, 0.f, 0.f};
    float D = 0.f;

    auto LD = [&](int ebase, uint4& h4, float& al) {
        int ee = ebase + g;
        int ie = (ee < e1) ? ee : e1 - 1;
        int s = csr[ie];
        float av = als[s * 4 + hd];
        al = (ee < e1) ? av : -1e30f;
        h4 = *(const uint4*)(hq + (size_t)s * 128);
    };
    auto PROC = [&](const uint4& h4, float al) {
        float lg = al + ad;
        lg = fmaxf(lg, 0.2f * lg);
        float exv = exp2f(lg);
        D += exv;
        const __half2* hh = (const __half2*)&h4;
#pragma unroll
        for (int i = 0; i < 4; ++i) {
            float2 f = __half22float2(hh[i]);
            acc[2 * i] = fmaf(exv, f.x, acc[2 * i]);
            acc[2 * i + 1] = fmaf(exv, f.y, acc[2 * i + 1]);
        }
    };

    uint4 hA, hB;
    float alA, alB;
    LD(e0, hA, alA);
    LD(e0 + 4, hB, alB);
    int e = e0;
    for (; e + 8 < e1; e += 8) {
        uint4 nA, nB;
        float nalA, nalB;
        LD(e + 8, nA, nalA);
        LD(e + 12, nB, nalB);
        PROC(hA, alA);
        PROC(hB, alB);
        hA = nA; alA = nalA;
        hB = nB; alB = nalB;
    }
    PROC(hA, alA);
    PROC(hB, alB);

#pragma unroll
    for (int i = 0; i < 8; ++i) {
        acc[i] += __shfl_xor(acc[i], 16, 64);
        acc[i] += __shfl_xor(acc[i], 32, 64);
    }
    D += __shfl_xor(D, 16, 64);
    D += __shfl_xor(D, 32, 64);

    if (g == 0) {
        float inv = 1.f / D;
        alignas(16) __half2 ph[4];
#pragma unroll
        for (int i = 0; i < 4; ++i) {
            float2 bv = ((const float2*)bias)[q * 4 + i];
            float vx = acc[2 * i] * inv + bv.x;
            float vy = acc[2 * i + 1] * inv + bv.y;
            vx = vx > 0.f ? vx : (__expf(vx) - 1.f);
            vy = vy > 0.f ? vy : (__expf(vy) - 1.f);
            ph[i] = __floats2half2_rn(vx, vy);
        }
        *(uint4*)(out + (size_t)wid * 128 + q * 8) = *(uint4*)ph;
    }
}

// Layer-2 aggregation (C=64): 8 groups x 8 lanes, 8 edges/step, 2-stage
// pipeline (16 edges in flight); fused layer-3 head; writes packed {h3, als3'}
// and ald3' (pre-scaled by log2e).
__global__ void gat_agg_l2(const __half* __restrict__ h,
                           const float* __restrict__ als, const float* __restrict__ ald,
                           const float* __restrict__ bias,
                           const int* __restrict__ off, const int* __restrict__ csr,
                           const float* __restrict__ W3, const float* __restrict__ as3,
                           const float* __restrict__ ad3, float2* __restrict__ hs,
                           float* __restrict__ ald3, int n) {
    int wid = (blockIdx.x * blockDim.x + threadIdx.x) >> 6;
    int lane = threadIdx.x & 63;
    if (wid >= n) return;
    const int g = lane >> 3;    // edge sub-slot 0..7
    const int q = lane & 7;     // 8 channels at q*8
    const int hd = q >> 2;      // head
    float ad = ald[wid * 2 + hd];
    int e0 = off[wid], e1 = off[wid + 1];
    const __half* hq = h + q * 8;

    float acc[8] = {0.f, 0.f, 0.f, 0.f, 0.f, 0.f, 0.f, 0.f};
    float D = 0.f;

    auto LD = [&](int ebase, uint4& h4, float& al) {
        int ee = ebase + g;
        int ie = (ee < e1) ? ee : e1 - 1;
        int s = csr[ie];
        float av = als[s * 2 + hd];
        al = (ee < e1) ? av : -1e30f;
        h4 = *(const uint4*)(hq + (size_t)s * 64);
    };
    auto PROC = [&](const uint4& h4, float al) {
        float lg = al + ad;
        lg = fmaxf(lg, 0.2f * lg);
        float exv = exp2f(lg);
        D += exv;
        const __half2* hh = (const __half2*)&h4;
#pragma unroll
        for (int i = 0; i < 4; ++i) {
            float2 f = __half22float2(hh[i]);
            acc[2 * i] = fmaf(exv, f.x, acc[2 * i]);
            acc[2 * i + 1] = fmaf(exv, f.y, acc[2 * i + 1]);
        }
    };

    uint4 hA, hB;
    float alA, alB;
    LD(e0, hA, alA);
    LD(e0 + 8, hB, alB);
    int e = e0;
    for (; e + 16 < e1; e += 16) {
        uint4 nA, nB;
        float nalA, nalB;
        LD(e + 16, nA, nalA);
        LD(e + 24, nB, nalB);
        PROC(hA, alA);
        PROC(hB, alB);
        hA = nA; alA = nalA;
        hB = nB; alB = nalB;
    }
    PROC(hA, alA);
    PROC(hB, alB);

#pragma unroll
    for (int i = 0; i < 8; ++i) {
        acc[i] += __shfl_xor(acc[i], 8, 64);
        acc[i] += __shfl_xor(acc[i], 16, 64);
        acc[i] += __shfl_xor(acc[i], 32, 64);
    }
    D += __shfl_xor(D, 8, 64);
    D += __shfl_xor(D, 16, 64);
    D += __shfl_xor(D, 32, 64);

    // fused layer-3 head: r = sum_c elu(acc_c/D + b2_c) * W3_c
    float inv = 1.f / D;
    float r = 0.f;
#pragma unroll
    for (int i = 0; i < 8; ++i) {
        float v = acc[i] * inv + bias[q * 8 + i];
        v = v > 0.f ? v : (__expf(v) - 1.f);
        r = fmaf(v, W3[q * 8 + i], r);
    }
#pragma unroll
    for (int msk = 1; msk < 8; msk <<= 1) r += __shfl_xor(r, msk, 64);
    if (lane == 0) {
        hs[wid] = make_float2(r, r * as3[0] * LOG2E);  // {h3, als3'}
        ald3[wid] = r * ad3[0] * LOG2E;
    }
}

// Layer-3 aggregation: thread per node, 2-wide pipeline, packed 8B gather.
__global__ void gat_agg1(const float2* __restrict__ hs, const float* __restrict__ ald3,
                         const float* __restrict__ bias,
                         const int* __restrict__ off, const int* __restrict__ csr,
                         float* __restrict__ out, int n) {
    int i = blockIdx.x * blockDim.x + threadIdx.x;
    if (i >= n) return;
    float ad = ald3[i];
    int e0 = off[i], e1 = off[i + 1];
    float S = 0.f, D = 0.f;
    float2 g[2];
    float valid[2];
#pragma unroll
    for (int p = 0; p < 2; ++p) {
        int ee = e0 + p;
        int ie = (ee < e1) ? ee : e1 - 1;
        int s = csr[ie];
        g[p] = hs[s];
        valid[p] = (ee < e1) ? 0.f : -1e30f;
    }
    int e = e0;
    for (; e + 2 < e1; e += 2) {
#pragma unroll
        for (int p = 0; p < 2; ++p) {
            int ee = e + 2 + p;
            int ie = (ee < e1) ? ee : e1 - 1;
            int s = csr[ie];
            float2 ng = hs[s];
            float nvalid = (ee < e1) ? 0.f : -1e30f;
            float lg = g[p].y + ad + valid[p];
            lg = fmaxf(lg, 0.2f * lg);
            float exv = exp2f(lg);
            D += exv;
            S = fmaf(exv, g[p].x, S);
            g[p] = ng;
            valid[p] = nvalid;
        }
    }
#pragma unroll
    for (int p = 0; p < 2; ++p) {
        float lg = g[p].y + ad + valid[p];
        lg = fmaxf(lg, 0.2f * lg);
        float exv = exp2f(lg);
        D += exv;
        S = fmaf(exv, g[p].x, S);
    }
    out[i] = S / D + bias[0];
}

extern "C" void kernel_launch(void* const* d_in, const int* in_sizes, int n_in,
                              void* d_out, int out_size, void* d_ws, size_t ws_size,
                              hipStream_t stream) {
    const float* x   = (const float*)d_in[0];
    const int*   ei  = (const int*)d_in[1];
    const float* W1  = (const float*)d_in[2];
    const float* as1 = (const float*)d_in[3];
    const float* ad1 = (const float*)d_in[4];
    const float* b1  = (const float*)d_in[5];
    const float* W2  = (const float*)d_in[6];
    const float* as2 = (const float*)d_in[7];
    const float* ad2 = (const float*)d_in[8];
    const float* b2  = (const float*)d_in[9];
    const float* W3  = (const float*)d_in[10];
    const float* as3 = (const float*)d_in[11];
    const float* ad3 = (const float*)d_in[12];
    const float* b3  = (const float*)d_in[13];
    float* out = (float*)d_out;

    const int N = in_sizes[0] / F_IN;  // 50000
    const int E = in_sizes[1] / 2;     // 800000
    const int ET = E + N;

    char* w = (char*)d_ws;
    size_t o = 0;
    auto alloc = [&](size_t bytes) -> void* {
        void* p = w + o;
        o += (bytes + 255) & ~(size_t)255;
        return p;
    };
    __half* hbuf = (__half*)alloc((size_t)N * 128 * 2);  // h1; reused as h2
    __half* a1   = (__half*)alloc((size_t)N * 128 * 2);
    float2* hs   = (float2*)alloc((size_t)N * 8);        // {h3, als3'}
    float* als  = (float*)alloc((size_t)N * 4 * 4);
    float* ald  = (float*)alloc((size_t)N * 4 * 4);
    float* ald3 = (float*)alloc((size_t)N * 4);
    int* deg    = (int*)alloc((size_t)(N + 1) * 4);
    int* off    = (int*)alloc((size_t)(N + 1) * 4);
    int* cursor = (int*)alloc((size_t)N * 4);
    int* bsums  = (int*)alloc(1024);
    int* csr    = (int*)alloc((size_t)ET * 4);

    __half* h2 = hbuf;              // h1 dead after agg_l1

    const int* esrc = ei;
    const int* edst = ei + E;

    // ---- CSR offsets ----
    hipMemsetAsync(deg, 0, (size_t)(N + 1) * 4, stream);
    count_deg4<<<((E + 3) / 4 + 255) / 256, 256, 0, stream>>>(edst, deg, E);
    int n1 = N + 1;
    int nb = (n1 + SB - 1) / SB;
    scan1<<<nb, SB, 0, stream>>>(deg, off, bsums, n1, N);   // +1 self-loop each
    scan2<<<1, SB, 0, stream>>>(bsums, nb);
    scan3<<<nb, SB, 0, stream>>>(off, cursor, bsums, n1, N);

    const int gblk = (N + 127) / 128;

    // ---- Layer-1 GEMM fused with XCD-partitioned CSR scatter ----
    {
        int E4 = (E + 3) >> 2;
        int spg = (E4 + N + 511) / 512;   // blocks per partition
        int sblk = 8 * spg;
        gemm1_scatter<<<gblk + sblk, dim3(16, 32), 0, stream>>>(
            x, W1, as1, ad1, hbuf, als, ald, N, gblk,
            esrc, edst, cursor, csr, E, N);
    }

    // ---- Layer 1 aggregation (edge-group layout) ----
    gat_agg_l1<<<(N * 64 + 255) / 256, 256, 0, stream>>>(
        hbuf, als, ald, b1, off, csr, a1, N);

    // ---- Layer 2: GEMM (fp16 A) + aggregation (edge-group, fused l3 head) ----
    gemm_fused_h<64, 4, 2><<<gblk, dim3(16, 32), 0, stream>>>(
        a1, W2, as2, ad2, h2, als, ald, N);
    gat_agg_l2<<<(N * 64 + 255) / 256, 256, 0, stream>>>(
        h2, als, ald, b2, off, csr, W3, as3, ad3, hs, ald3, N);

    // ---- Layer 3: aggregation of packed scalar feature ----
    gat_agg1<<<(N + 255) / 256, 256, 0, stream>>>(hs, ald3, b3, off, csr, out, N);
}